// Round 1
// baseline (7746.878 us; speedup 1.0000x reference)
//
#include <hip/hip_runtime.h>
#include <hip/hip_bf16.h>
#include <math.h>

#define T_SEQ 2048
#define HID 2048
#define HQ 16
#define HKV 8
#define D_HEAD 128
#define HALF 64
#define SCALE_F 0.08838834764831845f
#define S_TILE 32

// ---------------- GEMM fp32: C = A(MxK) @ B(KxN) + bias[n] ----------------
__global__ __launch_bounds__(256)
void gemm_f32(const float* __restrict__ A, const float* __restrict__ B,
              const float* __restrict__ bias, float* __restrict__ C,
              int M, int N, int K)
{
  __shared__ float As[64][17];
  __shared__ float Bs[16][68];
  const int tid = threadIdx.x;
  const int bx = blockIdx.x * 64;
  const int by = blockIdx.y * 64;
  const int tr = tid >> 4;          // 0..15
  const int tc = tid & 15;          // 0..15
  const int arow = tid >> 2;        // 0..63
  const int acol = (tid & 3) * 4;   // 0,4,8,12
  const int brow = tid >> 4;        // 0..15
  const int bcol = (tid & 15) * 4;  // 0..60

  float acc[4][4];
  #pragma unroll
  for (int i = 0; i < 4; ++i)
    #pragma unroll
    for (int j = 0; j < 4; ++j) acc[i][j] = 0.f;

  for (int k0 = 0; k0 < K; k0 += 16) {
    float4 a4 = *reinterpret_cast<const float4*>(&A[(size_t)(by + arow) * K + k0 + acol]);
    float4 b4 = *reinterpret_cast<const float4*>(&B[(size_t)(k0 + brow) * N + bx + bcol]);
    As[arow][acol + 0] = a4.x; As[arow][acol + 1] = a4.y;
    As[arow][acol + 2] = a4.z; As[arow][acol + 3] = a4.w;
    Bs[brow][bcol + 0] = b4.x; Bs[brow][bcol + 1] = b4.y;
    Bs[brow][bcol + 2] = b4.z; Bs[brow][bcol + 3] = b4.w;
    __syncthreads();
    #pragma unroll
    for (int kk = 0; kk < 16; ++kk) {
      float a[4], b[4];
      #pragma unroll
      for (int i = 0; i < 4; ++i) a[i] = As[tr * 4 + i][kk];
      #pragma unroll
      for (int j = 0; j < 4; ++j) b[j] = Bs[kk][tc * 4 + j];
      #pragma unroll
      for (int i = 0; i < 4; ++i)
        #pragma unroll
        for (int j = 0; j < 4; ++j) acc[i][j] = fmaf(a[i], b[j], acc[i][j]);
    }
    __syncthreads();
  }
  #pragma unroll
  for (int i = 0; i < 4; ++i) {
    int row = by + tr * 4 + i;
    #pragma unroll
    for (int j = 0; j < 4; ++j) {
      int col = bx + tc * 4 + j;
      C[(size_t)row * N + col] = acc[i][j] + bias[col];
    }
  }
}

// ---------------- gate projection: g = hs @ Wg + bg  (T x HKV) ----------------
__global__ __launch_bounds__(64)
void gproj_kernel(const float* __restrict__ hs, const float* __restrict__ Wg,
                  const float* __restrict__ bg, float* __restrict__ g)
{
  const int o = blockIdx.x;          // 0 .. T*HKV-1
  const int t = o / HKV;
  const int h = o % HKV;
  const int lane = threadIdx.x;
  float p = 0.f;
  for (int c = lane; c < HID; c += 64)
    p = fmaf(hs[(size_t)t * HID + c], Wg[(size_t)c * HKV + h], p);
  #pragma unroll
  for (int off = 32; off; off >>= 1) p += __shfl_down(p, off, 64);
  if (lane == 0) g[o] = p + bg[h];
}

// ---------------- RoPE (NeoX): applied in-place to q and k ----------------
__global__ __launch_bounds__(256)
void rope_kernel(float* __restrict__ q, float* __restrict__ k)
{
  const int total = T_SEQ * (HQ + HKV) * HALF;
  int idx = blockIdx.x * blockDim.x + threadIdx.x;
  if (idx >= total) return;
  const int i = idx % HALF;
  const int rest = idx / HALF;
  const int head = rest % (HQ + HKV);
  const int t = rest / (HQ + HKV);
  const float inv_freq = powf(10000.0f, -(float)i / (float)HALF);
  const float freq = (float)t * inv_freq;
  const float c = cosf(freq);
  const float s = sinf(freq);
  float* base = (head < HQ)
      ? (q + ((size_t)t * HQ + head) * D_HEAD)
      : (k + ((size_t)t * HKV + (head - HQ)) * D_HEAD);
  const float x1 = base[i];
  const float x2 = base[i + HALF];
  base[i]        = x1 * c - x2 * s;
  base[i + HALF] = x2 * c + x1 * s;
}

// -------- log_sigmoid + inclusive cumsum over time, per KV head --------
__global__ __launch_bounds__(512)
void gscan_kernel(const float* __restrict__ gin, float* __restrict__ Gc)
{
  const int w = threadIdx.x >> 6;     // head 0..7
  const int lane = threadIdx.x & 63;
  float carry = 0.f;
  for (int c0 = 0; c0 < T_SEQ; c0 += 64) {
    const float x = gin[(size_t)(c0 + lane) * HKV + w];
    const float nx = -x;
    const float sp = (nx > 20.f) ? nx : log1pf(expf(nx));
    float val = -sp;                  // log_sigmoid(x)
    #pragma unroll
    for (int off = 1; off < 64; off <<= 1) {
      float other = __shfl_up(val, off, 64);
      if (lane >= off) val += other;
    }
    val += carry;
    Gc[(size_t)(c0 + lane) * HKV + w] = val;
    carry = __shfl(val, 63, 64);
  }
}

// ---------------- attention core ----------------
// out[t,h,:] = sum_{s<=t} ((q_t . k_s)*SCALE)^2 * exp(G_t - G_s) * v_s
__global__ __launch_bounds__(128)
void attn_kernel(const float* __restrict__ q, const float* __restrict__ k,
                 const float* __restrict__ v, const float* __restrict__ Gc,
                 float* __restrict__ out)
{
  const int h = blockIdx.x;
  const int t = blockIdx.y;
  const int hk = h >> 1;              // rep = HQ/HKV = 2
  const int tid = threadIdx.x;        // 0..127
  __shared__ float ks[S_TILE][D_HEAD + 1];
  __shared__ float vs[S_TILE][D_HEAD + 1];
  __shared__ float qs[D_HEAD];
  __shared__ float wpart[2][S_TILE];
  __shared__ float wvals[S_TILE];

  qs[tid] = q[((size_t)t * HQ + h) * D_HEAD + tid];
  const float Gt = Gc[t * HKV + hk];
  float acc = 0.f;

  for (int s0 = 0; s0 <= t; s0 += S_TILE) {
    const int ns = min(S_TILE, t - s0 + 1);
    __syncthreads();
    for (int idx = tid; idx < S_TILE * D_HEAD; idx += 128) {
      const int r = idx >> 7, c = idx & 127;
      if (r < ns) {
        const size_t off = ((size_t)(s0 + r) * HKV + hk) * D_HEAD + c;
        ks[r][c] = k[off];
        vs[r][c] = v[off];
      }
    }
    __syncthreads();
    if (tid < 64) {
      const int s = tid & 31, half = tid >> 5;
      float p = 0.f;
      if (s < ns) {
        #pragma unroll 8
        for (int d0 = 0; d0 < HALF; ++d0) {
          const int d = half * HALF + d0;
          p = fmaf(qs[d], ks[s][d], p);
        }
      }
      wpart[half][s] = p;
    }
    __syncthreads();
    if (tid < S_TILE) {
      float w = 0.f;
      if (tid < ns) {
        const float dot = (wpart[0][tid] + wpart[1][tid]) * SCALE_F;
        const float diff = Gt - Gc[(s0 + tid) * HKV + hk];
        w = dot * dot * __expf(diff);
      }
      wvals[tid] = w;
    }
    __syncthreads();
    for (int j = 0; j < ns; ++j)
      acc = fmaf(wvals[j], vs[j][tid], acc);
  }
  out[((size_t)t * HQ + h) * D_HEAD + tid] = acc;
}

extern "C" void kernel_launch(void* const* d_in, const int* in_sizes, int n_in,
                              void* d_out, int out_size, void* d_ws, size_t ws_size,
                              hipStream_t stream)
{
  const float* hs = (const float*)d_in[1];
  const float* Wq = (const float*)d_in[2];
  const float* bq = (const float*)d_in[3];
  const float* Wk = (const float*)d_in[4];
  const float* bk = (const float*)d_in[5];
  const float* Wv = (const float*)d_in[6];
  const float* bv = (const float*)d_in[7];
  const float* Wg = (const float*)d_in[8];
  const float* bg = (const float*)d_in[9];
  const float* Wo = (const float*)d_in[10];
  const float* bo = (const float*)d_in[11];
  float* outp = (float*)d_out;

  float* wsf  = (float*)d_ws;
  float* qbuf = wsf;                                  // T*HQ*D   = 4194304
  float* kbuf = qbuf + (size_t)T_SEQ * HQ * D_HEAD;   // T*HKV*D  = 2097152
  float* vbuf = kbuf + (size_t)T_SEQ * HKV * D_HEAD;  // T*HKV*D  = 2097152
  float* abuf = vbuf + (size_t)T_SEQ * HKV * D_HEAD;  // T*HQ*D   = 4194304
  float* gbuf = abuf + (size_t)T_SEQ * HQ * D_HEAD;   // T*HKV    = 16384
  float* Gcum = gbuf + (size_t)T_SEQ * HKV;           // T*HKV    = 16384

  // Projections (fp32 tiled GEMM)
  gemm_f32<<<dim3((HQ * D_HEAD) / 64, T_SEQ / 64), 256, 0, stream>>>(
      hs, Wq, bq, qbuf, T_SEQ, HQ * D_HEAD, HID);
  gemm_f32<<<dim3((HKV * D_HEAD) / 64, T_SEQ / 64), 256, 0, stream>>>(
      hs, Wk, bk, kbuf, T_SEQ, HKV * D_HEAD, HID);
  gemm_f32<<<dim3((HKV * D_HEAD) / 64, T_SEQ / 64), 256, 0, stream>>>(
      hs, Wv, bv, vbuf, T_SEQ, HKV * D_HEAD, HID);

  // Gate projection + log-sigmoid cumsum
  gproj_kernel<<<T_SEQ * HKV, 64, 0, stream>>>(hs, Wg, bg, gbuf);
  gscan_kernel<<<1, 512, 0, stream>>>(gbuf, Gcum);

  // RoPE on q and k (positions == arange(T), use row index)
  {
    const int total = T_SEQ * (HQ + HKV) * HALF;
    rope_kernel<<<(total + 255) / 256, 256, 0, stream>>>(qbuf, kbuf);
  }

  // Attention
  attn_kernel<<<dim3(HQ, T_SEQ), 128, 0, stream>>>(qbuf, kbuf, vbuf, Gcum, abuf);

  // Output projection -> d_out
  gemm_f32<<<dim3(HID / 64, T_SEQ / 64), 256, 0, stream>>>(
      abuf, Wo, bo, outp, T_SEQ, HID, HID);
}

// Round 2
// 991.591 us; speedup vs baseline: 7.8126x; 7.8126x over previous
//
#include <hip/hip_runtime.h>
#include <hip/hip_bf16.h>
#include <math.h>

#define T_SEQ 2048
#define HID 2048
#define HQ 16
#define HKV 8
#define D_HEAD 128
#define HALF 64
#define SCALE_F 0.08838834764831845f
#define QB 32
#define SB 32

// ---------------- GEMM fp32: C = A(MxK) @ B(KxN) + bias[n] ----------------
__global__ __launch_bounds__(256)
void gemm_f32(const float* __restrict__ A, const float* __restrict__ B,
              const float* __restrict__ bias, float* __restrict__ C,
              int M, int N, int K)
{
  __shared__ float As[64][17];
  __shared__ float Bs[16][68];
  const int tid = threadIdx.x;
  const int bx = blockIdx.x * 64;
  const int by = blockIdx.y * 64;
  const int tr = tid >> 4;          // 0..15
  const int tc = tid & 15;          // 0..15
  const int arow = tid >> 2;        // 0..63
  const int acol = (tid & 3) * 4;   // 0,4,8,12
  const int brow = tid >> 4;        // 0..15
  const int bcol = (tid & 15) * 4;  // 0..60

  float acc[4][4];
  #pragma unroll
  for (int i = 0; i < 4; ++i)
    #pragma unroll
    for (int j = 0; j < 4; ++j) acc[i][j] = 0.f;

  for (int k0 = 0; k0 < K; k0 += 16) {
    float4 a4 = *reinterpret_cast<const float4*>(&A[(size_t)(by + arow) * K + k0 + acol]);
    float4 b4 = *reinterpret_cast<const float4*>(&B[(size_t)(k0 + brow) * N + bx + bcol]);
    As[arow][acol + 0] = a4.x; As[arow][acol + 1] = a4.y;
    As[arow][acol + 2] = a4.z; As[arow][acol + 3] = a4.w;
    Bs[brow][bcol + 0] = b4.x; Bs[brow][bcol + 1] = b4.y;
    Bs[brow][bcol + 2] = b4.z; Bs[brow][bcol + 3] = b4.w;
    __syncthreads();
    #pragma unroll
    for (int kk = 0; kk < 16; ++kk) {
      float a[4], b[4];
      #pragma unroll
      for (int i = 0; i < 4; ++i) a[i] = As[tr * 4 + i][kk];
      #pragma unroll
      for (int j = 0; j < 4; ++j) b[j] = Bs[kk][tc * 4 + j];
      #pragma unroll
      for (int i = 0; i < 4; ++i)
        #pragma unroll
        for (int j = 0; j < 4; ++j) acc[i][j] = fmaf(a[i], b[j], acc[i][j]);
    }
    __syncthreads();
  }
  #pragma unroll
  for (int i = 0; i < 4; ++i) {
    int row = by + tr * 4 + i;
    #pragma unroll
    for (int j = 0; j < 4; ++j) {
      int col = bx + tc * 4 + j;
      C[(size_t)row * N + col] = acc[i][j] + bias[col];
    }
  }
}

// ---------------- gate projection: g = hs @ Wg + bg  (T x HKV) ----------------
__global__ __launch_bounds__(64)
void gproj_kernel(const float* __restrict__ hs, const float* __restrict__ Wg,
                  const float* __restrict__ bg, float* __restrict__ g)
{
  const int o = blockIdx.x;          // 0 .. T*HKV-1
  const int t = o / HKV;
  const int h = o % HKV;
  const int lane = threadIdx.x;
  float p = 0.f;
  for (int c = lane; c < HID; c += 64)
    p = fmaf(hs[(size_t)t * HID + c], Wg[(size_t)c * HKV + h], p);
  #pragma unroll
  for (int off = 32; off; off >>= 1) p += __shfl_down(p, off, 64);
  if (lane == 0) g[o] = p + bg[h];
}

// ---------------- RoPE (NeoX): applied in-place to q and k ----------------
__global__ __launch_bounds__(256)
void rope_kernel(float* __restrict__ q, float* __restrict__ k)
{
  const int total = T_SEQ * (HQ + HKV) * HALF;
  int idx = blockIdx.x * blockDim.x + threadIdx.x;
  if (idx >= total) return;
  const int i = idx % HALF;
  const int rest = idx / HALF;
  const int head = rest % (HQ + HKV);
  const int t = rest / (HQ + HKV);
  const float inv_freq = powf(10000.0f, -(float)i / (float)HALF);
  const float freq = (float)t * inv_freq;
  const float c = cosf(freq);
  const float s = sinf(freq);
  float* base = (head < HQ)
      ? (q + ((size_t)t * HQ + head) * D_HEAD)
      : (k + ((size_t)t * HKV + (head - HQ)) * D_HEAD);
  const float x1 = base[i];
  const float x2 = base[i + HALF];
  base[i]        = x1 * c - x2 * s;
  base[i + HALF] = x2 * c + x1 * s;
}

// -------- log_sigmoid + inclusive cumsum over time, per KV head --------
__global__ __launch_bounds__(512)
void gscan_kernel(const float* __restrict__ gin, float* __restrict__ Gc)
{
  const int w = threadIdx.x >> 6;     // head 0..7
  const int lane = threadIdx.x & 63;
  float carry = 0.f;
  for (int c0 = 0; c0 < T_SEQ; c0 += 64) {
    const float x = gin[(size_t)(c0 + lane) * HKV + w];
    const float nx = -x;
    const float sp = (nx > 20.f) ? nx : log1pf(expf(nx));
    float val = -sp;                  // log_sigmoid(x)
    #pragma unroll
    for (int off = 1; off < 64; off <<= 1) {
      float other = __shfl_up(val, off, 64);
      if (lane >= off) val += other;
    }
    val += carry;
    Gc[(size_t)(c0 + lane) * HKV + w] = val;
    carry = __shfl(val, 63, 64);
  }
}

// ---------------- attention core (flash-style tiles) ----------------
// out[t,h,:] = sum_{s<=t} ((q_t . k_s)*SCALE)^2 * exp(G_t - G_s) * v_s
// One block per (head, 32-row q tile). 256 threads.
__global__ __launch_bounds__(256)
void attn_kernel(const float* __restrict__ q, const float* __restrict__ k,
                 const float* __restrict__ v, const float* __restrict__ Gc,
                 float* __restrict__ out)
{
  const int h = blockIdx.x;           // 0..15
  const int qt = blockIdx.y;          // 0..63
  const int hk = h >> 1;              // rep = 2
  const int tid = threadIdx.x;        // 0..255
  const int t0 = qt * QB;

  __shared__ float qs[QB][D_HEAD + 4];
  __shared__ float ks_[SB][D_HEAD + 4];
  __shared__ float vs[SB][D_HEAD + 4];
  __shared__ float Ws[QB][SB + 1];
  __shared__ float Gts[QB];
  __shared__ float Gss[SB];

  // stage q tile + G_t
  for (int idx = tid; idx < QB * (D_HEAD / 4); idx += 256) {
    const int r = idx >> 5;             // /32
    const int c4 = (idx & 31) * 4;
    *reinterpret_cast<float4*>(&qs[r][c4]) =
        *reinterpret_cast<const float4*>(&q[((size_t)(t0 + r) * HQ + h) * D_HEAD + c4]);
  }
  if (tid < QB) Gts[tid] = Gc[(t0 + tid) * HKV + hk];

  // QK mapping: 2x2 micro-tile
  const int r2 = (tid >> 4) * 2;        // 0..30
  const int c2 = (tid & 15) * 2;        // 0..30
  // PV mapping: row rpv, 16 consecutive cols
  const int rpv = tid >> 3;             // 0..31
  const int cbase = (tid & 7) * 16;     // 0..112

  float acc[16];
  #pragma unroll
  for (int j = 0; j < 16; ++j) acc[j] = 0.f;

  const float gt_first = Gc[t0 * HKV + hk];   // largest G among this q tile

  for (int s0 = 0; s0 <= t0; s0 += SB) {
    // decay-window skip: if even the closest (t,s) pair in this tile has
    // G_t - G_s < -90, every W underflows to (fp32) zero -> skip exactly.
    // Block-uniform (same global reads), touches no LDS.
    const float gs_last = Gc[(s0 + SB - 1) * HKV + hk];
    if (gt_first - gs_last < -90.0f) continue;

    __syncthreads();   // protect previous iteration's vs/Ws reads
    for (int idx = tid; idx < SB * (D_HEAD / 4); idx += 256) {
      const int r = idx >> 5;
      const int c4 = (idx & 31) * 4;
      const size_t off = ((size_t)(s0 + r) * HKV + hk) * D_HEAD + c4;
      *reinterpret_cast<float4*>(&ks_[r][c4]) = *reinterpret_cast<const float4*>(&k[off]);
      *reinterpret_cast<float4*>(&vs[r][c4])  = *reinterpret_cast<const float4*>(&v[off]);
    }
    if (tid < SB) Gss[tid] = Gc[(s0 + tid) * HKV + hk];
    __syncthreads();

    // QK^T (2x2 register block)
    float s00 = 0.f, s01 = 0.f, s10 = 0.f, s11 = 0.f;
    #pragma unroll 8
    for (int kk = 0; kk < D_HEAD; kk += 4) {
      const float4 qa = *reinterpret_cast<const float4*>(&qs[r2][kk]);
      const float4 qb = *reinterpret_cast<const float4*>(&qs[r2 + 1][kk]);
      const float4 ka = *reinterpret_cast<const float4*>(&ks_[c2][kk]);
      const float4 kb = *reinterpret_cast<const float4*>(&ks_[c2 + 1][kk]);
      s00 = fmaf(qa.x, ka.x, s00); s00 = fmaf(qa.y, ka.y, s00);
      s00 = fmaf(qa.z, ka.z, s00); s00 = fmaf(qa.w, ka.w, s00);
      s01 = fmaf(qa.x, kb.x, s01); s01 = fmaf(qa.y, kb.y, s01);
      s01 = fmaf(qa.z, kb.z, s01); s01 = fmaf(qa.w, kb.w, s01);
      s10 = fmaf(qb.x, ka.x, s10); s10 = fmaf(qb.y, ka.y, s10);
      s10 = fmaf(qb.z, ka.z, s10); s10 = fmaf(qb.w, ka.w, s10);
      s11 = fmaf(qb.x, kb.x, s11); s11 = fmaf(qb.y, kb.y, s11);
      s11 = fmaf(qb.z, kb.z, s11); s11 = fmaf(qb.w, kb.w, s11);
    }

    // W = (S*scale)^2 * exp(Gt - Gs), causal mask only matters on diagonal tile
    const bool diag = (s0 == t0);
    const float gt0 = Gts[r2],     gt1 = Gts[r2 + 1];
    const float gs0 = Gss[c2],     gs1 = Gss[c2 + 1];
    {
      float d;
      d = s00 * SCALE_F;
      Ws[r2][c2]         = (!diag || (c2     <= r2    )) ? d * d * __expf(gt0 - gs0) : 0.f;
      d = s01 * SCALE_F;
      Ws[r2][c2 + 1]     = (!diag || (c2 + 1 <= r2    )) ? d * d * __expf(gt0 - gs1) : 0.f;
      d = s10 * SCALE_F;
      Ws[r2 + 1][c2]     = (!diag || (c2     <= r2 + 1)) ? d * d * __expf(gt1 - gs0) : 0.f;
      d = s11 * SCALE_F;
      Ws[r2 + 1][c2 + 1] = (!diag || (c2 + 1 <= r2 + 1)) ? d * d * __expf(gt1 - gs1) : 0.f;
    }
    __syncthreads();

    // PV: acc[rpv, cbase..cbase+15] += W[rpv][s] * V[s][cbase..]
    #pragma unroll 4
    for (int s = 0; s < SB; ++s) {
      const float w = Ws[rpv][s];
      const float4 v0 = *reinterpret_cast<const float4*>(&vs[s][cbase]);
      const float4 v1 = *reinterpret_cast<const float4*>(&vs[s][cbase + 4]);
      const float4 v2 = *reinterpret_cast<const float4*>(&vs[s][cbase + 8]);
      const float4 v3 = *reinterpret_cast<const float4*>(&vs[s][cbase + 12]);
      acc[0]  = fmaf(w, v0.x, acc[0]);  acc[1]  = fmaf(w, v0.y, acc[1]);
      acc[2]  = fmaf(w, v0.z, acc[2]);  acc[3]  = fmaf(w, v0.w, acc[3]);
      acc[4]  = fmaf(w, v1.x, acc[4]);  acc[5]  = fmaf(w, v1.y, acc[5]);
      acc[6]  = fmaf(w, v1.z, acc[6]);  acc[7]  = fmaf(w, v1.w, acc[7]);
      acc[8]  = fmaf(w, v2.x, acc[8]);  acc[9]  = fmaf(w, v2.y, acc[9]);
      acc[10] = fmaf(w, v2.z, acc[10]); acc[11] = fmaf(w, v2.w, acc[11]);
      acc[12] = fmaf(w, v3.x, acc[12]); acc[13] = fmaf(w, v3.y, acc[13]);
      acc[14] = fmaf(w, v3.z, acc[14]); acc[15] = fmaf(w, v3.w, acc[15]);
    }
  }

  float* op = &out[((size_t)(t0 + rpv) * HQ + h) * D_HEAD + cbase];
  *reinterpret_cast<float4*>(op)      = make_float4(acc[0],  acc[1],  acc[2],  acc[3]);
  *reinterpret_cast<float4*>(op + 4)  = make_float4(acc[4],  acc[5],  acc[6],  acc[7]);
  *reinterpret_cast<float4*>(op + 8)  = make_float4(acc[8],  acc[9],  acc[10], acc[11]);
  *reinterpret_cast<float4*>(op + 12) = make_float4(acc[12], acc[13], acc[14], acc[15]);
}

extern "C" void kernel_launch(void* const* d_in, const int* in_sizes, int n_in,
                              void* d_out, int out_size, void* d_ws, size_t ws_size,
                              hipStream_t stream)
{
  const float* hs = (const float*)d_in[1];
  const float* Wq = (const float*)d_in[2];
  const float* bq = (const float*)d_in[3];
  const float* Wk = (const float*)d_in[4];
  const float* bk = (const float*)d_in[5];
  const float* Wv = (const float*)d_in[6];
  const float* bv = (const float*)d_in[7];
  const float* Wg = (const float*)d_in[8];
  const float* bg = (const float*)d_in[9];
  const float* Wo = (const float*)d_in[10];
  const float* bo = (const float*)d_in[11];
  float* outp = (float*)d_out;

  float* wsf  = (float*)d_ws;
  float* qbuf = wsf;                                  // T*HQ*D   = 4194304
  float* kbuf = qbuf + (size_t)T_SEQ * HQ * D_HEAD;   // T*HKV*D  = 2097152
  float* vbuf = kbuf + (size_t)T_SEQ * HKV * D_HEAD;  // T*HKV*D  = 2097152
  float* abuf = vbuf + (size_t)T_SEQ * HKV * D_HEAD;  // T*HQ*D   = 4194304
  float* gbuf = abuf + (size_t)T_SEQ * HQ * D_HEAD;   // T*HKV    = 16384
  float* Gcum = gbuf + (size_t)T_SEQ * HKV;           // T*HKV    = 16384

  // Projections (fp32 tiled GEMM)
  gemm_f32<<<dim3((HQ * D_HEAD) / 64, T_SEQ / 64), 256, 0, stream>>>(
      hs, Wq, bq, qbuf, T_SEQ, HQ * D_HEAD, HID);
  gemm_f32<<<dim3((HKV * D_HEAD) / 64, T_SEQ / 64), 256, 0, stream>>>(
      hs, Wk, bk, kbuf, T_SEQ, HKV * D_HEAD, HID);
  gemm_f32<<<dim3((HKV * D_HEAD) / 64, T_SEQ / 64), 256, 0, stream>>>(
      hs, Wv, bv, vbuf, T_SEQ, HKV * D_HEAD, HID);

  // Gate projection + log-sigmoid cumsum
  gproj_kernel<<<T_SEQ * HKV, 64, 0, stream>>>(hs, Wg, bg, gbuf);
  gscan_kernel<<<1, 512, 0, stream>>>(gbuf, Gcum);

  // RoPE on q and k (positions == arange(T), use row index)
  {
    const int total = T_SEQ * (HQ + HKV) * HALF;
    rope_kernel<<<(total + 255) / 256, 256, 0, stream>>>(qbuf, kbuf);
  }

  // Attention (flash-style)
  attn_kernel<<<dim3(HQ, T_SEQ / QB), 256, 0, stream>>>(qbuf, kbuf, vbuf, Gcum, abuf);

  // Output projection -> d_out
  gemm_f32<<<dim3(HID / 64, T_SEQ / 64), 256, 0, stream>>>(
      abuf, Wo, bo, outp, T_SEQ, HID, HID);
}

// Round 3
// 351.090 us; speedup vs baseline: 22.0652x; 2.8243x over previous
//
#include <hip/hip_runtime.h>
#include <hip/hip_bf16.h>
#include <math.h>

#define T_SEQ 2048
#define HID 2048
#define HQ 16
#define HKV 8
#define D_HEAD 128
#define HALF 64
#define SCALE_F 0.08838834764831845f
#define QB 32
#define SB 32

typedef __attribute__((ext_vector_type(8))) short bf16x8;
typedef __attribute__((ext_vector_type(4))) float f32x4;

static __device__ __forceinline__ short f2bf(float x) {
  unsigned u = __builtin_bit_cast(unsigned, x);
  unsigned r = (u + 0x7FFF + ((u >> 16) & 1)) >> 16;   // RNE
  return (short)r;
}

// ---------------- elementwise fp32 -> bf16 ----------------
__global__ __launch_bounds__(256)
void cvt_bf16(const float* __restrict__ in, short* __restrict__ out, int n4)
{
  int i = blockIdx.x * blockDim.x + threadIdx.x;
  if (i >= n4) return;
  float4 v = reinterpret_cast<const float4*>(in)[i];
  short4 o;
  o.x = f2bf(v.x); o.y = f2bf(v.y); o.z = f2bf(v.z); o.w = f2bf(v.w);
  reinterpret_cast<short4*>(out)[i] = o;
}

// ------------- transpose fp32 [K][N] -> bf16 [N][out_ld] -------------
__global__ __launch_bounds__(256)
void transpose_to_bf16(const float* __restrict__ in, short* __restrict__ out,
                       int N, int out_ld)
{
  __shared__ float tile[32][33];
  const int k0 = blockIdx.y * 32, n0 = blockIdx.x * 32;
  const int r = threadIdx.x >> 5, c = threadIdx.x & 31;
  #pragma unroll
  for (int i = 0; i < 4; ++i)
    tile[r + i * 8][c] = in[(size_t)(k0 + r + i * 8) * N + n0 + c];
  __syncthreads();
  #pragma unroll
  for (int i = 0; i < 4; ++i)
    out[(size_t)(n0 + r + i * 8) * out_ld + k0 + c] = f2bf(tile[c][r + i * 8]);
}

// ---------------- bf16 MFMA GEMM (m97 structure) ----------------
// C[M][N] = A[M][K](bf16) @ BT[N][K](bf16)^T + bias ; C fp32
// 128x128 tile, BK=32, 256 threads (4 waves, 2x2 wave grid, 4x4 frags each)
#define GLDS(gsrc, ldst) \
  __builtin_amdgcn_global_load_lds((const __attribute__((address_space(1))) void*)(gsrc), \
                                   (__attribute__((address_space(3))) void*)(ldst), 16, 0, 0)

__global__ __launch_bounds__(256)
void gemm_bf16(const short* __restrict__ A, const short* __restrict__ BT,
               const float* __restrict__ bias0, const float* __restrict__ bias1,
               int nsplit, float* __restrict__ C, int M, int N, int K)
{
  __shared__ short As[2][128 * 32];
  __shared__ short Bs[2][128 * 32];
  const int tid = threadIdx.x;
  const int wave = tid >> 6, lane = tid & 63;
  const int bm0 = blockIdx.y * 128, bn0 = blockIdx.x * 128;
  const int wm = (wave >> 1) * 64, wn = (wave & 1) * 64;

  // staging: wave stages rows [wave*32, wave*32+32) of both tiles
  const int srow = wave * 32 + (lane >> 2);
  const int scol = (lane & 3) * 8;                 // shorts
  const short* Abase = A + (size_t)(bm0 + srow) * K + scol;
  const short* Bbase = BT + (size_t)(bn0 + srow) * K + scol;

  f32x4 acc[4][4] = {};

  const int nk = K >> 5;
#define STAGE(buf, k0)                                                        \
  do {                                                                        \
    GLDS(Abase + (k0), &As[buf][(wave * 32) * 32]);                           \
    GLDS(Abase + (k0) + (size_t)16 * K, &As[buf][(wave * 32 + 16) * 32]);     \
    GLDS(Bbase + (k0), &Bs[buf][(wave * 32) * 32]);                           \
    GLDS(Bbase + (k0) + (size_t)16 * K, &Bs[buf][(wave * 32 + 16) * 32]);     \
  } while (0)

  STAGE(0, 0);
  __syncthreads();

  const int kof = (lane >> 4) * 8;
  const int rA = wm + (lane & 15);
  const int rB = wn + (lane & 15);

  for (int t = 0; t < nk; ++t) {
    const int cur = t & 1;
    if (t + 1 < nk) STAGE(cur ^ 1, (t + 1) << 5);
    bf16x8 af[4], bfr[4];
    #pragma unroll
    for (int i = 0; i < 4; ++i) {
      af[i]  = *reinterpret_cast<const bf16x8*>(&As[cur][(rA + i * 16) * 32 + kof]);
      bfr[i] = *reinterpret_cast<const bf16x8*>(&Bs[cur][(rB + i * 16) * 32 + kof]);
    }
    #pragma unroll
    for (int i = 0; i < 4; ++i)
      #pragma unroll
      for (int j = 0; j < 4; ++j)
        acc[i][j] = __builtin_amdgcn_mfma_f32_16x16x32_bf16(af[i], bfr[j], acc[i][j], 0, 0, 0);
    __syncthreads();
  }

  const int crow = wm + (lane >> 4) * 4;
  const int ccol = wn + (lane & 15);
  #pragma unroll
  for (int j = 0; j < 4; ++j) {
    const int col = bn0 + ccol + j * 16;
    const float b = (col < nsplit) ? bias0[col] : bias1[col - nsplit];
    #pragma unroll
    for (int i = 0; i < 4; ++i)
      #pragma unroll
      for (int r = 0; r < 4; ++r) {
        const int row = bm0 + crow + i * 16 + r;
        C[(size_t)row * N + col] = acc[i][j][r] + b;
      }
  }
#undef STAGE
}

// ---------------- gate projection: g = hs @ Wg + bg  (T x HKV) ----------------
__global__ __launch_bounds__(64)
void gproj_kernel(const float* __restrict__ hs, const float* __restrict__ Wg,
                  const float* __restrict__ bg, float* __restrict__ g)
{
  const int o = blockIdx.x;
  const int t = o / HKV;
  const int h = o % HKV;
  const int lane = threadIdx.x;
  float p = 0.f;
  for (int c = lane; c < HID; c += 64)
    p = fmaf(hs[(size_t)t * HID + c], Wg[(size_t)c * HKV + h], p);
  #pragma unroll
  for (int off = 32; off; off >>= 1) p += __shfl_down(p, off, 64);
  if (lane == 0) g[o] = p + bg[h];
}

// ---------------- RoPE (NeoX), in-place on q and kv(k half) ----------------
__global__ __launch_bounds__(256)
void rope_kernel(float* __restrict__ q, float* __restrict__ kv)
{
  const int total = T_SEQ * (HQ + HKV) * HALF;
  int idx = blockIdx.x * blockDim.x + threadIdx.x;
  if (idx >= total) return;
  const int i = idx % HALF;
  const int rest = idx / HALF;
  const int head = rest % (HQ + HKV);
  const int t = rest / (HQ + HKV);
  const float inv_freq = powf(10000.0f, -(float)i / (float)HALF);
  const float freq = (float)t * inv_freq;
  const float c = cosf(freq);
  const float s = sinf(freq);
  float* base = (head < HQ)
      ? (q + ((size_t)t * HQ + head) * D_HEAD)
      : (kv + (size_t)t * 2048 + (head - HQ) * D_HEAD);
  const float x1 = base[i];
  const float x2 = base[i + HALF];
  base[i]        = x1 * c - x2 * s;
  base[i + HALF] = x2 * c + x1 * s;
}

// -------- log_sigmoid + inclusive cumsum over time, per KV head --------
__global__ __launch_bounds__(512)
void gscan_kernel(const float* __restrict__ gin, float* __restrict__ Gc)
{
  const int w = threadIdx.x >> 6;
  const int lane = threadIdx.x & 63;
  float carry = 0.f;
  for (int c0 = 0; c0 < T_SEQ; c0 += 64) {
    const float x = gin[(size_t)(c0 + lane) * HKV + w];
    const float nx = -x;
    const float sp = (nx > 20.f) ? nx : log1pf(expf(nx));
    float val = -sp;
    #pragma unroll
    for (int off = 1; off < 64; off <<= 1) {
      float other = __shfl_up(val, off, 64);
      if (lane >= off) val += other;
    }
    val += carry;
    Gc[(size_t)(c0 + lane) * HKV + w] = val;
    carry = __shfl(val, 63, 64);
  }
}

// ---------------- attention core (flash-style tiles) ----------------
// kv layout: [T][2048], cols [hk*128..] = k head hk, [1024 + hk*128..] = v head hk
// output written as bf16 [T][HQ*128]
__global__ __launch_bounds__(256)
void attn_kernel(const float* __restrict__ q, const float* __restrict__ kv,
                 const float* __restrict__ Gc, short* __restrict__ outb)
{
  const int h = blockIdx.x;
  const int qt = blockIdx.y;
  const int hk = h >> 1;
  const int tid = threadIdx.x;
  const int t0 = qt * QB;

  __shared__ float qs[QB][D_HEAD + 4];
  __shared__ float ks_[SB][D_HEAD + 4];
  __shared__ float vs[SB][D_HEAD + 4];
  __shared__ float Ws[QB][SB + 1];
  __shared__ float Gts[QB];
  __shared__ float Gss[SB];

  for (int idx = tid; idx < QB * (D_HEAD / 4); idx += 256) {
    const int r = idx >> 5;
    const int c4 = (idx & 31) * 4;
    *reinterpret_cast<float4*>(&qs[r][c4]) =
        *reinterpret_cast<const float4*>(&q[((size_t)(t0 + r) * HQ + h) * D_HEAD + c4]);
  }
  if (tid < QB) Gts[tid] = Gc[(t0 + tid) * HKV + hk];

  const int r2 = (tid >> 4) * 2;
  const int c2 = (tid & 15) * 2;
  const int rpv = tid >> 3;
  const int cbase = (tid & 7) * 16;

  float acc[16];
  #pragma unroll
  for (int j = 0; j < 16; ++j) acc[j] = 0.f;

  const float gt_first = Gc[t0 * HKV + hk];

  for (int s0 = 0; s0 <= t0; s0 += SB) {
    const float gs_last = Gc[(s0 + SB - 1) * HKV + hk];
    if (gt_first - gs_last < -90.0f) continue;   // exp underflows to exactly 0

    __syncthreads();
    for (int idx = tid; idx < SB * (D_HEAD / 4); idx += 256) {
      const int r = idx >> 5;
      const int c4 = (idx & 31) * 4;
      const float* row = &kv[(size_t)(s0 + r) * 2048 + hk * D_HEAD + c4];
      *reinterpret_cast<float4*>(&ks_[r][c4]) = *reinterpret_cast<const float4*>(row);
      *reinterpret_cast<float4*>(&vs[r][c4])  = *reinterpret_cast<const float4*>(row + 1024);
    }
    if (tid < SB) Gss[tid] = Gc[(s0 + tid) * HKV + hk];
    __syncthreads();

    float s00 = 0.f, s01 = 0.f, s10 = 0.f, s11 = 0.f;
    #pragma unroll 8
    for (int kk = 0; kk < D_HEAD; kk += 4) {
      const float4 qa = *reinterpret_cast<const float4*>(&qs[r2][kk]);
      const float4 qb = *reinterpret_cast<const float4*>(&qs[r2 + 1][kk]);
      const float4 ka = *reinterpret_cast<const float4*>(&ks_[c2][kk]);
      const float4 kb = *reinterpret_cast<const float4*>(&ks_[c2 + 1][kk]);
      s00 = fmaf(qa.x, ka.x, s00); s00 = fmaf(qa.y, ka.y, s00);
      s00 = fmaf(qa.z, ka.z, s00); s00 = fmaf(qa.w, ka.w, s00);
      s01 = fmaf(qa.x, kb.x, s01); s01 = fmaf(qa.y, kb.y, s01);
      s01 = fmaf(qa.z, kb.z, s01); s01 = fmaf(qa.w, kb.w, s01);
      s10 = fmaf(qb.x, ka.x, s10); s10 = fmaf(qb.y, ka.y, s10);
      s10 = fmaf(qb.z, ka.z, s10); s10 = fmaf(qb.w, ka.w, s10);
      s11 = fmaf(qb.x, kb.x, s11); s11 = fmaf(qb.y, kb.y, s11);
      s11 = fmaf(qb.z, kb.z, s11); s11 = fmaf(qb.w, kb.w, s11);
    }

    const bool diag = (s0 == t0);
    const float gt0 = Gts[r2], gt1 = Gts[r2 + 1];
    const float gs0 = Gss[c2], gs1 = Gss[c2 + 1];
    {
      float d;
      d = s00 * SCALE_F;
      Ws[r2][c2]         = (!diag || (c2     <= r2    )) ? d * d * __expf(gt0 - gs0) : 0.f;
      d = s01 * SCALE_F;
      Ws[r2][c2 + 1]     = (!diag || (c2 + 1 <= r2    )) ? d * d * __expf(gt0 - gs1) : 0.f;
      d = s10 * SCALE_F;
      Ws[r2 + 1][c2]     = (!diag || (c2     <= r2 + 1)) ? d * d * __expf(gt1 - gs0) : 0.f;
      d = s11 * SCALE_F;
      Ws[r2 + 1][c2 + 1] = (!diag || (c2 + 1 <= r2 + 1)) ? d * d * __expf(gt1 - gs1) : 0.f;
    }
    __syncthreads();

    #pragma unroll 4
    for (int s = 0; s < SB; ++s) {
      const float w = Ws[rpv][s];
      const float4 v0 = *reinterpret_cast<const float4*>(&vs[s][cbase]);
      const float4 v1 = *reinterpret_cast<const float4*>(&vs[s][cbase + 4]);
      const float4 v2 = *reinterpret_cast<const float4*>(&vs[s][cbase + 8]);
      const float4 v3 = *reinterpret_cast<const float4*>(&vs[s][cbase + 12]);
      acc[0]  = fmaf(w, v0.x, acc[0]);  acc[1]  = fmaf(w, v0.y, acc[1]);
      acc[2]  = fmaf(w, v0.z, acc[2]);  acc[3]  = fmaf(w, v0.w, acc[3]);
      acc[4]  = fmaf(w, v1.x, acc[4]);  acc[5]  = fmaf(w, v1.y, acc[5]);
      acc[6]  = fmaf(w, v1.z, acc[6]);  acc[7]  = fmaf(w, v1.w, acc[7]);
      acc[8]  = fmaf(w, v2.x, acc[8]);  acc[9]  = fmaf(w, v2.y, acc[9]);
      acc[10] = fmaf(w, v2.z, acc[10]); acc[11] = fmaf(w, v2.w, acc[11]);
      acc[12] = fmaf(w, v3.x, acc[12]); acc[13] = fmaf(w, v3.y, acc[13]);
      acc[14] = fmaf(w, v3.z, acc[14]); acc[15] = fmaf(w, v3.w, acc[15]);
    }
  }

  short* op = &outb[((size_t)(t0 + rpv) * HQ + h) * D_HEAD + cbase];
  #pragma unroll
  for (int b4 = 0; b4 < 4; ++b4) {
    short4 o;
    o.x = f2bf(acc[b4 * 4 + 0]); o.y = f2bf(acc[b4 * 4 + 1]);
    o.z = f2bf(acc[b4 * 4 + 2]); o.w = f2bf(acc[b4 * 4 + 3]);
    *reinterpret_cast<short4*>(op + b4 * 4) = o;
  }
}

extern "C" void kernel_launch(void* const* d_in, const int* in_sizes, int n_in,
                              void* d_out, int out_size, void* d_ws, size_t ws_size,
                              hipStream_t stream)
{
  const float* hs = (const float*)d_in[1];
  const float* Wq = (const float*)d_in[2];
  const float* bq = (const float*)d_in[3];
  const float* Wk = (const float*)d_in[4];
  const float* bk = (const float*)d_in[5];
  const float* Wv = (const float*)d_in[6];
  const float* bv = (const float*)d_in[7];
  const float* Wg = (const float*)d_in[8];
  const float* bg = (const float*)d_in[9];
  const float* Wo = (const float*)d_in[10];
  const float* bo = (const float*)d_in[11];
  float* outp = (float*)d_out;

  // fp32 region
  float* wsf  = (float*)d_ws;
  float* qbuf = wsf;                                   // 4M f
  float* kvbuf = qbuf + (size_t)T_SEQ * HQ * D_HEAD;   // 4M f  [T][2048] k|v
  float* gbuf = kvbuf + (size_t)T_SEQ * 2048;          // 16K f
  float* Gcum = gbuf + (size_t)T_SEQ * HKV;            // 16K f
  // bf16 region (shorts)
  short* s16 = (short*)(Gcum + (size_t)T_SEQ * HKV);
  short* S1 = s16;                       // 4M sh: hsb, later WoT
  short* S2 = S1 + (size_t)2048 * 2048;  // 4M sh: WqT, later attn-out(bf16)
  short* S3 = S2 + (size_t)2048 * 2048;  // 4M sh: WkT|WvT stacked

  // 1) conversions
  cvt_bf16<<<(2048 * 2048 / 4 + 255) / 256, 256, 0, stream>>>(hs, S1, 2048 * 2048 / 4);
  transpose_to_bf16<<<dim3(64, 64), 256, 0, stream>>>(Wq, S2, 2048, 2048);
  transpose_to_bf16<<<dim3(32, 64), 256, 0, stream>>>(Wk, S3, 1024, 2048);
  transpose_to_bf16<<<dim3(32, 64), 256, 0, stream>>>(Wv, S3 + (size_t)1024 * 2048, 1024, 2048);

  // 2) Q and fused-KV projections (bf16 MFMA)
  gemm_bf16<<<dim3(16, 16), 256, 0, stream>>>(S1, S2, bq, bq, 2048, qbuf, 2048, 2048, 2048);
  gemm_bf16<<<dim3(16, 16), 256, 0, stream>>>(S1, S3, bk, bv, 1024, kvbuf, 2048, 2048, 2048);

  // 3) Wo transpose (reuses hsb space — hsb dead after the GEMMs above)
  transpose_to_bf16<<<dim3(64, 64), 256, 0, stream>>>(Wo, S1, 2048, 2048);

  // 4) gate projection + log-sigmoid cumsum
  gproj_kernel<<<T_SEQ * HKV, 64, 0, stream>>>(hs, Wg, bg, gbuf);
  gscan_kernel<<<1, 512, 0, stream>>>(gbuf, Gcum);

  // 5) RoPE on q and k
  {
    const int total = T_SEQ * (HQ + HKV) * HALF;
    rope_kernel<<<(total + 255) / 256, 256, 0, stream>>>(qbuf, kvbuf);
  }

  // 6) attention -> bf16 output (into S2; WqT dead after Q GEMM)
  attn_kernel<<<dim3(HQ, T_SEQ / QB), 256, 0, stream>>>(qbuf, kvbuf, Gcum, S2);

  // 7) output projection -> d_out (fp32)
  gemm_bf16<<<dim3(16, 16), 256, 0, stream>>>(S2, S1, bo, bo, 2048, outp, 2048, 2048, 2048);
}

// Round 4
// 204.857 us; speedup vs baseline: 37.8161x; 1.7138x over previous
//
#include <hip/hip_runtime.h>
#include <hip/hip_bf16.h>
#include <math.h>

#define T_SEQ 2048
#define HID 2048
#define HQ 16
#define HKV 8
#define D_HEAD 128
#define HALF 64
#define SCALE_F 0.08838834764831845f

typedef __attribute__((ext_vector_type(8))) short bf16x8;
typedef __attribute__((ext_vector_type(4))) float f32x4;

static __device__ __forceinline__ short f2bf(float x) {
  unsigned u = __builtin_bit_cast(unsigned, x);
  unsigned r = (u + 0x7FFF + ((u >> 16) & 1)) >> 16;   // RNE
  return (short)r;
}
static __device__ __forceinline__ float bf2f(unsigned short u) {
  unsigned v = ((unsigned)u) << 16;
  return __builtin_bit_cast(float, v);
}

#define GLDS(gsrc, ldst) \
  __builtin_amdgcn_global_load_lds((const __attribute__((address_space(1))) void*)(gsrc), \
                                   (__attribute__((address_space(3))) void*)(ldst), 16, 0, 0)

// ---------------- elementwise fp32 -> bf16 ----------------
__global__ __launch_bounds__(256)
void cvt_bf16(const float* __restrict__ in, short* __restrict__ out, int n4)
{
  int i = blockIdx.x * blockDim.x + threadIdx.x;
  if (i >= n4) return;
  float4 v = reinterpret_cast<const float4*>(in)[i];
  short4 o;
  o.x = f2bf(v.x); o.y = f2bf(v.y); o.z = f2bf(v.z); o.w = f2bf(v.w);
  reinterpret_cast<short4*>(out)[i] = o;
}

// ------------- transpose fp32 [K][N] -> bf16 [N][out_ld] -------------
__global__ __launch_bounds__(256)
void transpose_to_bf16(const float* __restrict__ in, short* __restrict__ out,
                       int N, int out_ld)
{
  __shared__ float tile[32][33];
  const int k0 = blockIdx.y * 32, n0 = blockIdx.x * 32;
  const int r = threadIdx.x >> 5, c = threadIdx.x & 31;
  #pragma unroll
  for (int i = 0; i < 4; ++i)
    tile[r + i * 8][c] = in[(size_t)(k0 + r + i * 8) * N + n0 + c];
  __syncthreads();
  #pragma unroll
  for (int i = 0; i < 4; ++i)
    out[(size_t)(n0 + r + i * 8) * out_ld + k0 + c] = f2bf(tile[c][r + i * 8]);
}

// ---------------- bf16 MFMA GEMM (m97 structure) ----------------
// C[M][N] = A[M][K](bf16) @ BT[N][K](bf16)^T + bias ; C fp32 or bf16
template <bool OBF>
__global__ __launch_bounds__(256)
void gemm_bf16(const short* __restrict__ A, const short* __restrict__ BT,
               const float* __restrict__ bias0, const float* __restrict__ bias1,
               int nsplit, void* __restrict__ Cout, int M, int N, int K)
{
  __shared__ short As[2][128 * 32];
  __shared__ short Bs[2][128 * 32];
  const int tid = threadIdx.x;
  const int wave = tid >> 6, lane = tid & 63;
  const int bm0 = blockIdx.y * 128, bn0 = blockIdx.x * 128;
  const int wm = (wave >> 1) * 64, wn = (wave & 1) * 64;

  const int srow = wave * 32 + (lane >> 2);
  const int scol = (lane & 3) * 8;
  const short* Abase = A + (size_t)(bm0 + srow) * K + scol;
  const short* Bbase = BT + (size_t)(bn0 + srow) * K + scol;

  f32x4 acc[4][4] = {};

  const int nk = K >> 5;
#define STAGE(buf, k0)                                                        \
  do {                                                                        \
    GLDS(Abase + (k0), &As[buf][(wave * 32) * 32]);                           \
    GLDS(Abase + (k0) + (size_t)16 * K, &As[buf][(wave * 32 + 16) * 32]);     \
    GLDS(Bbase + (k0), &Bs[buf][(wave * 32) * 32]);                           \
    GLDS(Bbase + (k0) + (size_t)16 * K, &Bs[buf][(wave * 32 + 16) * 32]);     \
  } while (0)

  STAGE(0, 0);
  __syncthreads();

  const int kof = (lane >> 4) * 8;
  const int rA = wm + (lane & 15);
  const int rB = wn + (lane & 15);

  for (int t = 0; t < nk; ++t) {
    const int cur = t & 1;
    if (t + 1 < nk) STAGE(cur ^ 1, (t + 1) << 5);
    bf16x8 af[4], bfr[4];
    #pragma unroll
    for (int i = 0; i < 4; ++i) {
      af[i]  = *reinterpret_cast<const bf16x8*>(&As[cur][(rA + i * 16) * 32 + kof]);
      bfr[i] = *reinterpret_cast<const bf16x8*>(&Bs[cur][(rB + i * 16) * 32 + kof]);
    }
    #pragma unroll
    for (int i = 0; i < 4; ++i)
      #pragma unroll
      for (int j = 0; j < 4; ++j)
        acc[i][j] = __builtin_amdgcn_mfma_f32_16x16x32_bf16(af[i], bfr[j], acc[i][j], 0, 0, 0);
    __syncthreads();
  }

  const int crow = wm + (lane >> 4) * 4;
  const int ccol = wn + (lane & 15);
  #pragma unroll
  for (int j = 0; j < 4; ++j) {
    const int col = bn0 + ccol + j * 16;
    const float b = (col < nsplit) ? bias0[col] : bias1[col - nsplit];
    #pragma unroll
    for (int i = 0; i < 4; ++i)
      #pragma unroll
      for (int r = 0; r < 4; ++r) {
        const int row = bm0 + crow + i * 16 + r;
        const float v = acc[i][j][r] + b;
        if constexpr (OBF)
          ((short*)Cout)[(size_t)row * N + col] = f2bf(v);
        else
          ((float*)Cout)[(size_t)row * N + col] = v;
      }
  }
#undef STAGE
}

// ------------- gate projection: gT[h][t] = hs[t] . Wg[:,h] + bg -------------
__global__ __launch_bounds__(256)
void gproj_kernel(const float* __restrict__ hs, const float* __restrict__ Wg,
                  const float* __restrict__ bg, float* __restrict__ gT)
{
  const int t = blockIdx.x, tid = threadIdx.x;
  __shared__ float red[256][9];
  float a[8] = {0.f, 0.f, 0.f, 0.f, 0.f, 0.f, 0.f, 0.f};
  for (int cc = tid; cc < HID; cc += 256) {
    const float hv = hs[(size_t)t * HID + cc];
    const float4 w0 = *reinterpret_cast<const float4*>(Wg + (size_t)cc * 8);
    const float4 w1 = *reinterpret_cast<const float4*>(Wg + (size_t)cc * 8 + 4);
    a[0] = fmaf(hv, w0.x, a[0]); a[1] = fmaf(hv, w0.y, a[1]);
    a[2] = fmaf(hv, w0.z, a[2]); a[3] = fmaf(hv, w0.w, a[3]);
    a[4] = fmaf(hv, w1.x, a[4]); a[5] = fmaf(hv, w1.y, a[5]);
    a[6] = fmaf(hv, w1.z, a[6]); a[7] = fmaf(hv, w1.w, a[7]);
  }
  #pragma unroll
  for (int j = 0; j < 8; ++j) red[tid][j] = a[j];
  __syncthreads();
  for (int s = 128; s >= 1; s >>= 1) {
    if (tid < s) {
      #pragma unroll
      for (int j = 0; j < 8; ++j) red[tid][j] += red[tid + s][j];
    }
    __syncthreads();
  }
  if (tid < 8) gT[(size_t)tid * T_SEQ + t] = red[0][tid] + bg[tid];
}

// ------- log_sigmoid + inclusive cumsum, wave per head, LDS preload -------
__global__ __launch_bounds__(512)
void gscan_kernel(const float* __restrict__ gT, float* __restrict__ Gct)
{
  __shared__ float row[8][2048];
  const int wid = threadIdx.x >> 6, lane = threadIdx.x & 63;
  for (int j = lane; j < 512; j += 64)
    reinterpret_cast<float4*>(&row[wid][0])[j] =
        reinterpret_cast<const float4*>(gT + (size_t)wid * T_SEQ)[j];
  asm volatile("s_waitcnt lgkmcnt(0)" ::: "memory");
  __builtin_amdgcn_sched_barrier(0);
  float carry = 0.f;
  for (int c0 = 0; c0 < T_SEQ; c0 += 64) {
    const float x = row[wid][c0 + lane];
    const float nx = -x;
    const float sp = (nx > 20.f) ? nx : log1pf(expf(nx));
    float val = -sp;
    #pragma unroll
    for (int off = 1; off < 64; off <<= 1) {
      const float other = __shfl_up(val, off, 64);
      if (lane >= off) val += other;
    }
    val += carry;
    Gct[(size_t)wid * T_SEQ + c0 + lane] = val;
    carry = __shfl(val, 63, 64);
  }
}

// ---------------- RoPE (NeoX) on bf16 q and kv(k half), in place ----------------
__global__ __launch_bounds__(192)
void rope_kernel(short* __restrict__ q, short* __restrict__ kv)
{
  const int t = blockIdx.x;
  __shared__ float cs[64], sn[64];
  if (threadIdx.x < 64) {
    const int i = threadIdx.x;
    const float f = (float)t * powf(10000.0f, -(float)i / 64.0f);
    cs[i] = cosf(f); sn[i] = sinf(f);
  }
  __syncthreads();
  const int u = threadIdx.x;          // 0..191 = 24 heads x 8 chunks
  const int hh = u >> 3, ch = u & 7;
  short* base = (hh < HQ) ? q + ((size_t)t * HQ + hh) * D_HEAD
                          : kv + (size_t)t * 2048 + (hh - HQ) * D_HEAD;
  bf16x8 x1 = *reinterpret_cast<bf16x8*>(base + ch * 8);
  bf16x8 x2 = *reinterpret_cast<bf16x8*>(base + HALF + ch * 8);
  #pragma unroll
  for (int j = 0; j < 8; ++j) {
    const float a = bf2f((unsigned short)x1[j]);
    const float b = bf2f((unsigned short)x2[j]);
    const float cc = cs[ch * 8 + j], ss = sn[ch * 8 + j];
    x1[j] = f2bf(a * cc - b * ss);
    x2[j] = f2bf(b * cc + a * ss);
  }
  *reinterpret_cast<bf16x8*>(base + ch * 8) = x1;
  *reinterpret_cast<bf16x8*>(base + HALF + ch * 8) = x2;
}

// -------- V transpose: kv[t][1024 + hk*128 + d] -> Vt[hk][d][t] (bf16) --------
__global__ __launch_bounds__(256)
void vtrans_kernel(const unsigned short* __restrict__ kv, unsigned short* __restrict__ vt)
{
  __shared__ unsigned short tile[32][33];
  const int tt = blockIdx.x * 32, dd = blockIdx.y * 32, hk = blockIdx.z;
  const int c = threadIdx.x & 31, r0 = (threadIdx.x >> 5) * 4;
  #pragma unroll
  for (int i = 0; i < 4; ++i)
    tile[r0 + i][c] = kv[(size_t)(tt + r0 + i) * 2048 + 1024 + hk * 128 + dd + c];
  __syncthreads();
  #pragma unroll
  for (int i = 0; i < 4; ++i)
    vt[(size_t)(hk * 128 + dd + r0 + i) * T_SEQ + tt + c] = tile[c][r0 + i];
}

// ---------------- MFMA attention ----------------
// out[t,h,:] = sum_{s<=t} ((q_t.k_s)*SCALE)^2 * exp(G_t - G_s) * v_s
// Block: (hk, 64 q-rows), 4 waves = 2 heads x 2 q-subtiles of 32 rows.
// LDS: K[2][64][128] swz | Vt[2][128][64] swz | P[4][2][32][40] | Gss[2][64]
__global__ __launch_bounds__(256, 1)
void attn_mfma(const short* __restrict__ qb, const short* __restrict__ kvb,
               const short* __restrict__ vt, const float* __restrict__ Gct,
               short* __restrict__ outb)
{
  __shared__ __align__(16) char smem[86528];
  const int hk = blockIdx.x;
  const int tb = blockIdx.y * 64;
  const int tid = threadIdx.x;
  const int wid = tid >> 6, lane = tid & 63;
  const int c = lane & 15, g = lane >> 4;
  const int h = 2 * hk + (wid >> 1);
  const int tw = tb + (wid & 1) * 32;
  const float* Gh = Gct + (size_t)hk * T_SEQ;

  // decay-window start: smallest s with G[s] <= G[tb] + 90 (G monotone down).
  // Tiles before this underflow exp() to exactly 0 -> skipping is exact.
  const float glim = Gh[tb] + 90.0f;
  int lo = 0, hi = tb;
  while (lo < hi) {
    const int mid = (lo + hi) >> 1;
    if (Gh[mid] > glim) lo = mid + 1; else hi = mid;
  }
  const int sfirst = lo & ~63;
  const int nst = ((tb - sfirst) >> 6) + 1;

  // Q fragments (B-operand: row = t = lane&15 per 16-subtile, k contiguous)
  bf16x8 qf[2][4];
  #pragma unroll
  for (int tt = 0; tt < 2; ++tt)
    #pragma unroll
    for (int kb = 0; kb < 4; ++kb)
      qf[tt][kb] = *reinterpret_cast<const bf16x8*>(
          qb + ((size_t)(tw + 16 * tt + c) * HQ + h) * D_HEAD + kb * 32 + g * 8);
  const float gt0 = Gh[tw + c];
  const float gt1 = Gh[tw + 16 + c];
  const float gtw = Gh[tw];
  const int twmax = tw + 31;

  f32x4 accv[2][8] = {};

#define ASTG(buf, s64)                                                              \
  do {                                                                              \
    _Pragma("unroll")                                                               \
    for (int i2 = 0; i2 < 4; ++i2) {                                                \
      const int cid = tid + 256 * i2;                                               \
      const int kr = cid >> 4, kc = cid & 15;                                       \
      GLDS(kvb + (size_t)((s64) + kr) * 2048 + hk * 128 + ((kc ^ (kr & 7)) * 8),    \
           smem + (buf) * 16384 + cid * 16);                                        \
      const int vr = cid >> 3, vc = cid & 7;                                        \
      GLDS(vt + (size_t)(hk * 128 + vr) * T_SEQ + (s64) + ((vc ^ (vr & 7)) * 8),    \
           smem + 32768 + (buf) * 16384 + cid * 16);                                \
    }                                                                               \
    if (tid < 64) ((float*)(smem + 86016))[(buf) * 64 + tid] = Gh[(s64) + tid];     \
  } while (0)

  ASTG(0, sfirst);
  __syncthreads();

  for (int i = 0; i < nst; ++i) {
    const int cur = i & 1;
    if (i + 1 < nst) ASTG(cur ^ 1, sfirst + (i + 1) * 64);
    const int sbase64 = sfirst + i * 64;
    const float* Gss = (const float*)(smem + 86016) + cur * 64;
    char* Pmy = smem + 65536 + wid * 5120;

    #pragma unroll
    for (int st = 0; st < 2; ++st) {
      const int s0 = sbase64 + st * 32;
      if (s0 > twmax) continue;                       // fully above diagonal
      if (gtw - Gss[st * 32 + 31] < -90.0f) continue; // fully decayed (exact 0)

      // K fragments (A-operand: row = s, k contiguous), XOR-deswizzle
      bf16x8 kf[2][4];
      #pragma unroll
      for (int sg = 0; sg < 2; ++sg)
        #pragma unroll
        for (int kb = 0; kb < 4; ++kb) {
          const int row = st * 32 + 16 * sg + c;
          const int byt = (row * 256 + kb * 64 + g * 16) ^ ((c & 7) << 4);
          kf[sg][kb] = *reinterpret_cast<const bf16x8*>(smem + cur * 16384 + byt);
        }
      // S^T = K . Q^T  (lane holds col t = lane&15; rows s across regs)
      f32x4 sa[2][2] = {};
      #pragma unroll
      for (int kb = 0; kb < 4; ++kb)
        #pragma unroll
        for (int sg = 0; sg < 2; ++sg)
          #pragma unroll
          for (int tt = 0; tt < 2; ++tt)
            sa[sg][tt] = __builtin_amdgcn_mfma_f32_16x16x32_bf16(
                kf[sg][kb], qf[tt][kb], sa[sg][tt], 0, 0, 0);

      // W = (S*scale)^2 * exp(Gt-Gs), causal mask; pack bf16 -> P LDS [t][s]
      #pragma unroll
      for (int sg = 0; sg < 2; ++sg) {
        const float4 gs = *reinterpret_cast<const float4*>(&Gss[st * 32 + sg * 16 + g * 4]);
        const float gsv[4] = {gs.x, gs.y, gs.z, gs.w};
        #pragma unroll
        for (int tt = 0; tt < 2; ++tt) {
          const int tg = tw + 16 * tt + c;
          const float gt = tt ? gt1 : gt0;
          const int sg0 = s0 + sg * 16 + g * 4;
          float w[4];
          #pragma unroll
          for (int r = 0; r < 4; ++r) {
            const float dv = sa[sg][tt][r] * SCALE_F;
            const float ww = dv * dv * __expf(gt - gsv[r]);
            w[r] = (sg0 + r <= tg) ? ww : 0.0f;
          }
          uint2 pv;
          pv.x = ((unsigned)(unsigned short)f2bf(w[1]) << 16) | (unsigned short)f2bf(w[0]);
          pv.y = ((unsigned)(unsigned short)f2bf(w[3]) << 16) | (unsigned short)f2bf(w[2]);
          *reinterpret_cast<uint2*>(Pmy + st * 2560 + (c + 16 * tt) * 80 + 8 * g + 32 * sg) = pv;
        }
      }
      // wave-private LDS round trip: wait writes (cross-lane within wave)
      asm volatile("s_waitcnt lgkmcnt(0)" ::: "memory");
      __builtin_amdgcn_sched_barrier(0);

      bf16x8 pf[2];
      #pragma unroll
      for (int tt = 0; tt < 2; ++tt)
        pf[tt] = *reinterpret_cast<const bf16x8*>(Pmy + st * 2560 + (c + 16 * tt) * 80 + g * 16);

      // PV: out[t][d] += P . Vt^T
      #pragma unroll
      for (int db = 0; db < 8; ++db) {
        const int row = 16 * db + c;
        const int byt = (row * 128 + st * 64 + g * 16) ^ ((c & 7) << 4);
        const bf16x8 vf = *reinterpret_cast<const bf16x8*>(smem + 32768 + cur * 16384 + byt);
        #pragma unroll
        for (int tt = 0; tt < 2; ++tt)
          accv[tt][db] = __builtin_amdgcn_mfma_f32_16x16x32_bf16(pf[tt], vf, accv[tt][db], 0, 0, 0);
      }
    }
    __syncthreads();
  }

  // epilogue: acc -> LDS (overlay staging bufs, stride 136 bf16) -> bf16 global
  char* Wme = smem + wid * 8704;
  #pragma unroll
  for (int tt = 0; tt < 2; ++tt)
    #pragma unroll
    for (int db = 0; db < 8; ++db)
      #pragma unroll
      for (int r = 0; r < 4; ++r)
        *reinterpret_cast<short*>(Wme + (16 * tt + 4 * g + r) * 272 + (16 * db + c) * 2)
            = f2bf(accv[tt][db][r]);
  asm volatile("s_waitcnt lgkmcnt(0)" ::: "memory");
  __builtin_amdgcn_sched_barrier(0);
  #pragma unroll
  for (int e = 0; e < 8; ++e) {
    const int idx = e * 64 + lane;
    const int tr = idx >> 4, d0 = (idx & 15) * 8;
    const bf16x8 vv = *reinterpret_cast<const bf16x8*>(Wme + tr * 272 + d0 * 2);
    *reinterpret_cast<bf16x8*>(outb + ((size_t)(tw + tr) * HQ + h) * D_HEAD + d0) = vv;
  }
#undef ASTG
}

extern "C" void kernel_launch(void* const* d_in, const int* in_sizes, int n_in,
                              void* d_out, int out_size, void* d_ws, size_t ws_size,
                              hipStream_t stream)
{
  const float* hs = (const float*)d_in[1];
  const float* Wq = (const float*)d_in[2];
  const float* bq = (const float*)d_in[3];
  const float* Wk = (const float*)d_in[4];
  const float* bk = (const float*)d_in[5];
  const float* Wv = (const float*)d_in[6];
  const float* bv = (const float*)d_in[7];
  const float* Wg = (const float*)d_in[8];
  const float* bg = (const float*)d_in[9];
  const float* Wo = (const float*)d_in[10];
  const float* bo = (const float*)d_in[11];
  float* outp = (float*)d_out;

  // workspace carve (~48.1 MB)
  short* qb  = (short*)d_ws;                    // [T][16][128] bf16
  short* kvb = qb + (size_t)4194304;            // [T][2048] bf16 (k|v)
  short* vtb = kvb + (size_t)4194304;           // [8][128][T] bf16 (V^T)
  float* gT  = (float*)(vtb + (size_t)4194304); // [8][T] f32
  float* Gct = gT + 16384;                      // [8][T] f32
  short* S1  = (short*)(Gct + 16384);           // hsb -> WoT
  short* S2  = S1 + (size_t)4194304;            // WqT -> attn-out
  short* S3  = S2 + (size_t)4194304;            // WkT|WvT

  cvt_bf16<<<4096, 256, 0, stream>>>(hs, S1, 1048576);
  transpose_to_bf16<<<dim3(64, 64), 256, 0, stream>>>(Wq, S2, 2048, 2048);
  transpose_to_bf16<<<dim3(32, 64), 256, 0, stream>>>(Wk, S3, 1024, 2048);
  transpose_to_bf16<<<dim3(32, 64), 256, 0, stream>>>(Wv, S3 + (size_t)1024 * 2048, 1024, 2048);

  gemm_bf16<true><<<dim3(16, 16), 256, 0, stream>>>(S1, S2, bq, bq, 2048, qb, 2048, 2048, 2048);
  gemm_bf16<true><<<dim3(16, 16), 256, 0, stream>>>(S1, S3, bk, bv, 1024, kvb, 2048, 2048, 2048);

  transpose_to_bf16<<<dim3(64, 64), 256, 0, stream>>>(Wo, S1, 2048, 2048);  // hsb dead

  gproj_kernel<<<2048, 256, 0, stream>>>(hs, Wg, bg, gT);
  gscan_kernel<<<1, 512, 0, stream>>>(gT, Gct);

  rope_kernel<<<2048, 192, 0, stream>>>(qb, kvb);
  vtrans_kernel<<<dim3(64, 4, 8), 256, 0, stream>>>((const unsigned short*)kvb,
                                                    (unsigned short*)vtb);

  attn_mfma<<<dim3(8, 32), 256, 0, stream>>>(qb, kvb, vtb, Gct, S2);

  gemm_bf16<false><<<dim3(16, 16), 256, 0, stream>>>(S2, S1, bo, bo, 2048, outp, 2048, 2048, 2048);
}

// Round 5
// 187.410 us; speedup vs baseline: 41.3365x; 1.0931x over previous
//
#include <hip/hip_runtime.h>
#include <hip/hip_bf16.h>
#include <math.h>

#define T_SEQ 2048
#define HID 2048
#define HQ 16
#define HKV 8
#define D_HEAD 128
#define HALF 64
#define SCALE_F 0.08838834764831845f

typedef __attribute__((ext_vector_type(8))) short bf16x8;
typedef __attribute__((ext_vector_type(4))) float f32x4;

static __device__ __forceinline__ short f2bf(float x) {
  unsigned u = __builtin_bit_cast(unsigned, x);
  unsigned r = (u + 0x7FFF + ((u >> 16) & 1)) >> 16;   // RNE
  return (short)r;
}
static __device__ __forceinline__ float bf2f(unsigned short u) {
  unsigned v = ((unsigned)u) << 16;
  return __builtin_bit_cast(float, v);
}

#define GLDS(gsrc, ldst) \
  __builtin_amdgcn_global_load_lds((const __attribute__((address_space(1))) void*)(gsrc), \
                                   (__attribute__((address_space(3))) void*)(ldst), 16, 0, 0)

// ---------------- elementwise fp32 -> bf16 ----------------
__global__ __launch_bounds__(256)
void cvt_bf16(const float* __restrict__ in, short* __restrict__ out, int n4)
{
  int i = blockIdx.x * blockDim.x + threadIdx.x;
  if (i >= n4) return;
  float4 v = reinterpret_cast<const float4*>(in)[i];
  short4 o;
  o.x = f2bf(v.x); o.y = f2bf(v.y); o.z = f2bf(v.z); o.w = f2bf(v.w);
  reinterpret_cast<short4*>(out)[i] = o;
}

// ------------- transpose fp32 [K][N] -> bf16 [N][out_ld] -------------
__global__ __launch_bounds__(256)
void transpose_to_bf16(const float* __restrict__ in, short* __restrict__ out,
                       int N, int out_ld)
{
  __shared__ float tile[32][33];
  const int k0 = blockIdx.y * 32, n0 = blockIdx.x * 32;
  const int r = threadIdx.x >> 5, c = threadIdx.x & 31;
  #pragma unroll
  for (int i = 0; i < 4; ++i)
    tile[r + i * 8][c] = in[(size_t)(k0 + r + i * 8) * N + n0 + c];
  __syncthreads();
  #pragma unroll
  for (int i = 0; i < 4; ++i)
    out[(size_t)(n0 + r + i * 8) * out_ld + k0 + c] = f2bf(tile[c][r + i * 8]);
}

// ---------------- bf16 MFMA GEMM (m97 structure) ----------------
// C[M][N] = A[M][K](bf16) @ BT[N][K](bf16)^T + bias ; C fp32 or bf16
template <bool OBF>
__global__ __launch_bounds__(256)
void gemm_bf16(const short* __restrict__ A, const short* __restrict__ BT,
               const float* __restrict__ bias0, const float* __restrict__ bias1,
               int nsplit, void* __restrict__ Cout, int M, int N, int K)
{
  __shared__ short As[2][128 * 32];
  __shared__ short Bs[2][128 * 32];
  const int tid = threadIdx.x;
  const int wave = tid >> 6, lane = tid & 63;
  const int bm0 = blockIdx.y * 128, bn0 = blockIdx.x * 128;
  const int wm = (wave >> 1) * 64, wn = (wave & 1) * 64;

  const int srow = wave * 32 + (lane >> 2);
  const int scol = (lane & 3) * 8;
  const short* Abase = A + (size_t)(bm0 + srow) * K + scol;
  const short* Bbase = BT + (size_t)(bn0 + srow) * K + scol;

  f32x4 acc[4][4] = {};

  const int nk = K >> 5;
#define STAGE(buf, k0)                                                        \
  do {                                                                        \
    GLDS(Abase + (k0), &As[buf][(wave * 32) * 32]);                           \
    GLDS(Abase + (k0) + (size_t)16 * K, &As[buf][(wave * 32 + 16) * 32]);     \
    GLDS(Bbase + (k0), &Bs[buf][(wave * 32) * 32]);                           \
    GLDS(Bbase + (k0) + (size_t)16 * K, &Bs[buf][(wave * 32 + 16) * 32]);     \
  } while (0)

  STAGE(0, 0);
  __syncthreads();

  const int kof = (lane >> 4) * 8;
  const int rA = wm + (lane & 15);
  const int rB = wn + (lane & 15);

  for (int t = 0; t < nk; ++t) {
    const int cur = t & 1;
    if (t + 1 < nk) STAGE(cur ^ 1, (t + 1) << 5);
    bf16x8 af[4], bfr[4];
    #pragma unroll
    for (int i = 0; i < 4; ++i) {
      af[i]  = *reinterpret_cast<const bf16x8*>(&As[cur][(rA + i * 16) * 32 + kof]);
      bfr[i] = *reinterpret_cast<const bf16x8*>(&Bs[cur][(rB + i * 16) * 32 + kof]);
    }
    #pragma unroll
    for (int i = 0; i < 4; ++i)
      #pragma unroll
      for (int j = 0; j < 4; ++j)
        acc[i][j] = __builtin_amdgcn_mfma_f32_16x16x32_bf16(af[i], bfr[j], acc[i][j], 0, 0, 0);
    __syncthreads();
  }

  const int crow = wm + (lane >> 4) * 4;
  const int ccol = wn + (lane & 15);
  #pragma unroll
  for (int j = 0; j < 4; ++j) {
    const int col = bn0 + ccol + j * 16;
    const float b = (col < nsplit) ? bias0[col] : bias1[col - nsplit];
    #pragma unroll
    for (int i = 0; i < 4; ++i)
      #pragma unroll
      for (int r = 0; r < 4; ++r) {
        const int row = bm0 + crow + i * 16 + r;
        const float v = acc[i][j][r] + b;
        if constexpr (OBF)
          ((short*)Cout)[(size_t)row * N + col] = f2bf(v);
        else
          ((float*)Cout)[(size_t)row * N + col] = v;
      }
  }
#undef STAGE
}

// ------------- gate projection + log-sigmoid fused -------------
// gT[h][t] = log_sigmoid(hs[t] . Wg[:,h] + bg[h])
__global__ __launch_bounds__(256)
void gproj_kernel(const float* __restrict__ hs, const float* __restrict__ Wg,
                  const float* __restrict__ bg, float* __restrict__ gT)
{
  const int t = blockIdx.x, tid = threadIdx.x;
  __shared__ float red[256][9];
  float a[8] = {0.f, 0.f, 0.f, 0.f, 0.f, 0.f, 0.f, 0.f};
  for (int cc = tid; cc < HID; cc += 256) {
    const float hv = hs[(size_t)t * HID + cc];
    const float4 w0 = *reinterpret_cast<const float4*>(Wg + (size_t)cc * 8);
    const float4 w1 = *reinterpret_cast<const float4*>(Wg + (size_t)cc * 8 + 4);
    a[0] = fmaf(hv, w0.x, a[0]); a[1] = fmaf(hv, w0.y, a[1]);
    a[2] = fmaf(hv, w0.z, a[2]); a[3] = fmaf(hv, w0.w, a[3]);
    a[4] = fmaf(hv, w1.x, a[4]); a[5] = fmaf(hv, w1.y, a[5]);
    a[6] = fmaf(hv, w1.z, a[6]); a[7] = fmaf(hv, w1.w, a[7]);
  }
  #pragma unroll
  for (int j = 0; j < 8; ++j) red[tid][j] = a[j];
  __syncthreads();
  for (int s = 128; s >= 1; s >>= 1) {
    if (tid < s) {
      #pragma unroll
      for (int j = 0; j < 8; ++j) red[tid][j] += red[tid + s][j];
    }
    __syncthreads();
  }
  if (tid < 8) {
    const float x = red[0][tid] + bg[tid];
    const float nx = -x;
    const float sp = (nx > 20.f) ? nx : log1pf(expf(nx));
    gT[(size_t)tid * T_SEQ + t] = -sp;      // log_sigmoid(x)
  }
}

// ------- parallel inclusive cumsum over T per head (input already logsigmoid) -------
// 8 blocks (one per head) x 512 threads; 4 elements per thread.
__global__ __launch_bounds__(512)
void gscan_kernel(const float* __restrict__ gT, float* __restrict__ Gct)
{
  const int h = blockIdx.x;
  const int tid = threadIdx.x;
  const int wid = tid >> 6, lane = tid & 63;
  __shared__ float wsum[8];

  const float4 v = reinterpret_cast<const float4*>(gT + (size_t)h * T_SEQ)[tid];
  const float p0 = v.x, p1 = p0 + v.y, p2 = p1 + v.z, p3 = p2 + v.w;

  // wave-inclusive scan of thread totals
  float sc = p3;
  #pragma unroll
  for (int off = 1; off < 64; off <<= 1) {
    const float o = __shfl_up(sc, off, 64);
    if (lane >= off) sc += o;
  }
  if (lane == 63) wsum[wid] = sc;
  __syncthreads();
  float wof = 0.f;
  #pragma unroll
  for (int w = 0; w < 8; ++w) wof += (w < wid) ? wsum[w] : 0.f;

  const float excl = wof + sc - p3;
  reinterpret_cast<float4*>(Gct + (size_t)h * T_SEQ)[tid] =
      make_float4(excl + p0, excl + p1, excl + p2, excl + p3);
}

// ---------------- RoPE (NeoX) on bf16 q and kv(k half), in place ----------------
__global__ __launch_bounds__(192)
void rope_kernel(short* __restrict__ q, short* __restrict__ kv)
{
  const int t = blockIdx.x;
  __shared__ float cs[64], sn[64];
  if (threadIdx.x < 64) {
    const int i = threadIdx.x;
    const float f = (float)t * powf(10000.0f, -(float)i / 64.0f);
    cs[i] = cosf(f); sn[i] = sinf(f);
  }
  __syncthreads();
  const int u = threadIdx.x;          // 0..191 = 24 heads x 8 chunks
  const int hh = u >> 3, ch = u & 7;
  short* base = (hh < HQ) ? q + ((size_t)t * HQ + hh) * D_HEAD
                          : kv + (size_t)t * 2048 + (hh - HQ) * D_HEAD;
  bf16x8 x1 = *reinterpret_cast<bf16x8*>(base + ch * 8);
  bf16x8 x2 = *reinterpret_cast<bf16x8*>(base + HALF + ch * 8);
  #pragma unroll
  for (int j = 0; j < 8; ++j) {
    const float a = bf2f((unsigned short)x1[j]);
    const float b = bf2f((unsigned short)x2[j]);
    const float cc = cs[ch * 8 + j], ss = sn[ch * 8 + j];
    x1[j] = f2bf(a * cc - b * ss);
    x2[j] = f2bf(b * cc + a * ss);
  }
  *reinterpret_cast<bf16x8*>(base + ch * 8) = x1;
  *reinterpret_cast<bf16x8*>(base + HALF + ch * 8) = x2;
}

// -------- V transpose: kv[t][1024 + hk*128 + d] -> Vt[hk][d][t] (bf16) --------
__global__ __launch_bounds__(256)
void vtrans_kernel(const unsigned short* __restrict__ kv, unsigned short* __restrict__ vt)
{
  __shared__ unsigned short tile[32][33];
  const int tt = blockIdx.x * 32, dd = blockIdx.y * 32, hk = blockIdx.z;
  const int c = threadIdx.x & 31, r0 = (threadIdx.x >> 5) * 4;
  #pragma unroll
  for (int i = 0; i < 4; ++i)
    tile[r0 + i][c] = kv[(size_t)(tt + r0 + i) * 2048 + 1024 + hk * 128 + dd + c];
  __syncthreads();
  #pragma unroll
  for (int i = 0; i < 4; ++i)
    vt[(size_t)(hk * 128 + dd + r0 + i) * T_SEQ + tt + c] = tile[c][r0 + i];
}

// ---------------- MFMA attention ----------------
// out[t,h,:] = sum_{s<=t} ((q_t.k_s)*SCALE)^2 * exp(G_t - G_s) * v_s
// Block: (hk, 64 q-rows), 4 waves = 2 heads x 2 q-subtiles of 32 rows.
// LDS: K[2][64][128] swz | Vt[2][128][64] swz | P[4][2][32][40] | Gss[2][64]
__global__ __launch_bounds__(256, 1)
void attn_mfma(const short* __restrict__ qb, const short* __restrict__ kvb,
               const short* __restrict__ vt, const float* __restrict__ Gct,
               short* __restrict__ outb)
{
  __shared__ __align__(16) char smem[86528];
  const int hk = blockIdx.x;
  const int tb = blockIdx.y * 64;
  const int tid = threadIdx.x;
  const int wid = tid >> 6, lane = tid & 63;
  const int c = lane & 15, g = lane >> 4;
  const int h = 2 * hk + (wid >> 1);
  const int tw = tb + (wid & 1) * 32;
  const float* Gh = Gct + (size_t)hk * T_SEQ;

  // decay-window start: smallest s with G[s] <= G[tb] + 90 (G monotone down).
  const float glim = Gh[tb] + 90.0f;
  int lo = 0, hi = tb;
  while (lo < hi) {
    const int mid = (lo + hi) >> 1;
    if (Gh[mid] > glim) lo = mid + 1; else hi = mid;
  }
  const int sfirst = lo & ~63;
  const int nst = ((tb - sfirst) >> 6) + 1;

  // Q fragments (B-operand: row = t = lane&15 per 16-subtile, k contiguous)
  bf16x8 qf[2][4];
  #pragma unroll
  for (int tt = 0; tt < 2; ++tt)
    #pragma unroll
    for (int kb = 0; kb < 4; ++kb)
      qf[tt][kb] = *reinterpret_cast<const bf16x8*>(
          qb + ((size_t)(tw + 16 * tt + c) * HQ + h) * D_HEAD + kb * 32 + g * 8);
  const float gt0 = Gh[tw + c];
  const float gt1 = Gh[tw + 16 + c];
  const float gtw = Gh[tw];
  const int twmax = tw + 31;

  f32x4 accv[2][8] = {};

#define ASTG(buf, s64)                                                              \
  do {                                                                              \
    _Pragma("unroll")                                                               \
    for (int i2 = 0; i2 < 4; ++i2) {                                                \
      const int cid = tid + 256 * i2;                                               \
      const int kr = cid >> 4, kc = cid & 15;                                       \
      GLDS(kvb + (size_t)((s64) + kr) * 2048 + hk * 128 + ((kc ^ (kr & 7)) * 8),    \
           smem + (buf) * 16384 + cid * 16);                                        \
      const int vr = cid >> 3, vc = cid & 7;                                        \
      GLDS(vt + (size_t)(hk * 128 + vr) * T_SEQ + (s64) + ((vc ^ (vr & 7)) * 8),    \
           smem + 32768 + (buf) * 16384 + cid * 16);                                \
    }                                                                               \
    if (tid < 64) ((float*)(smem + 86016))[(buf) * 64 + tid] = Gh[(s64) + tid];     \
  } while (0)

  ASTG(0, sfirst);
  __syncthreads();

  for (int i = 0; i < nst; ++i) {
    const int cur = i & 1;
    if (i + 1 < nst) ASTG(cur ^ 1, sfirst + (i + 1) * 64);
    const int sbase64 = sfirst + i * 64;
    const float* Gss = (const float*)(smem + 86016) + cur * 64;
    char* Pmy = smem + 65536 + wid * 5120;

    #pragma unroll
    for (int st = 0; st < 2; ++st) {
      const int s0 = sbase64 + st * 32;
      if (s0 > twmax) continue;                       // fully above diagonal
      if (gtw - Gss[st * 32 + 31] < -90.0f) continue; // fully decayed (exact 0)

      // K fragments (A-operand: row = s, k contiguous), XOR-deswizzle
      bf16x8 kf[2][4];
      #pragma unroll
      for (int sg = 0; sg < 2; ++sg)
        #pragma unroll
        for (int kb = 0; kb < 4; ++kb) {
          const int row = st * 32 + 16 * sg + c;
          const int byt = (row * 256 + kb * 64 + g * 16) ^ ((c & 7) << 4);
          kf[sg][kb] = *reinterpret_cast<const bf16x8*>(smem + cur * 16384 + byt);
        }
      // S^T = K . Q^T  (lane holds col t = lane&15; rows s across regs)
      f32x4 sa[2][2] = {};
      #pragma unroll
      for (int kb = 0; kb < 4; ++kb)
        #pragma unroll
        for (int sg = 0; sg < 2; ++sg)
          #pragma unroll
          for (int tt = 0; tt < 2; ++tt)
            sa[sg][tt] = __builtin_amdgcn_mfma_f32_16x16x32_bf16(
                kf[sg][kb], qf[tt][kb], sa[sg][tt], 0, 0, 0);

      // W = (S*scale)^2 * exp(Gt-Gs), causal mask; pack bf16 -> P LDS [t][s]
      #pragma unroll
      for (int sg = 0; sg < 2; ++sg) {
        const float4 gs = *reinterpret_cast<const float4*>(&Gss[st * 32 + sg * 16 + g * 4]);
        const float gsv[4] = {gs.x, gs.y, gs.z, gs.w};
        #pragma unroll
        for (int tt = 0; tt < 2; ++tt) {
          const int tg = tw + 16 * tt + c;
          const float gt = tt ? gt1 : gt0;
          const int sg0 = s0 + sg * 16 + g * 4;
          float w[4];
          #pragma unroll
          for (int r = 0; r < 4; ++r) {
            const float dv = sa[sg][tt][r] * SCALE_F;
            const float ww = dv * dv * __expf(gt - gsv[r]);
            w[r] = (sg0 + r <= tg) ? ww : 0.0f;
          }
          uint2 pv;
          pv.x = ((unsigned)(unsigned short)f2bf(w[1]) << 16) | (unsigned short)f2bf(w[0]);
          pv.y = ((unsigned)(unsigned short)f2bf(w[3]) << 16) | (unsigned short)f2bf(w[2]);
          *reinterpret_cast<uint2*>(Pmy + st * 2560 + (c + 16 * tt) * 80 + 8 * g + 32 * sg) = pv;
        }
      }
      // wave-private LDS round trip: wait writes (cross-lane within wave)
      asm volatile("s_waitcnt lgkmcnt(0)" ::: "memory");
      __builtin_amdgcn_sched_barrier(0);

      bf16x8 pf[2];
      #pragma unroll
      for (int tt = 0; tt < 2; ++tt)
        pf[tt] = *reinterpret_cast<const bf16x8*>(Pmy + st * 2560 + (c + 16 * tt) * 80 + g * 16);

      // PV: out[t][d] += P . Vt^T
      #pragma unroll
      for (int db = 0; db < 8; ++db) {
        const int row = 16 * db + c;
        const int byt = (row * 128 + st * 64 + g * 16) ^ ((c & 7) << 4);
        const bf16x8 vf = *reinterpret_cast<const bf16x8*>(smem + 32768 + cur * 16384 + byt);
        #pragma unroll
        for (int tt = 0; tt < 2; ++tt)
          accv[tt][db] = __builtin_amdgcn_mfma_f32_16x16x32_bf16(pf[tt], vf, accv[tt][db], 0, 0, 0);
      }
    }
    __syncthreads();
  }

  // epilogue: acc -> LDS (overlay staging bufs, stride 136 bf16) -> bf16 global
  char* Wme = smem + wid * 8704;
  #pragma unroll
  for (int tt = 0; tt < 2; ++tt)
    #pragma unroll
    for (int db = 0; db < 8; ++db)
      #pragma unroll
      for (int r = 0; r < 4; ++r)
        *reinterpret_cast<short*>(Wme + (16 * tt + 4 * g + r) * 272 + (16 * db + c) * 2)
            = f2bf(accv[tt][db][r]);
  asm volatile("s_waitcnt lgkmcnt(0)" ::: "memory");
  __builtin_amdgcn_sched_barrier(0);
  #pragma unroll
  for (int e = 0; e < 8; ++e) {
    const int idx = e * 64 + lane;
    const int tr = idx >> 4, d0 = (idx & 15) * 8;
    const bf16x8 vv = *reinterpret_cast<const bf16x8*>(Wme + tr * 272 + d0 * 2);
    *reinterpret_cast<bf16x8*>(outb + ((size_t)(tw + tr) * HQ + h) * D_HEAD + d0) = vv;
  }
#undef ASTG
}

extern "C" void kernel_launch(void* const* d_in, const int* in_sizes, int n_in,
                              void* d_out, int out_size, void* d_ws, size_t ws_size,
                              hipStream_t stream)
{
  const float* hs = (const float*)d_in[1];
  const float* Wq = (const float*)d_in[2];
  const float* bq = (const float*)d_in[3];
  const float* Wk = (const float*)d_in[4];
  const float* bk = (const float*)d_in[5];
  const float* Wv = (const float*)d_in[6];
  const float* bv = (const float*)d_in[7];
  const float* Wg = (const float*)d_in[8];
  const float* bg = (const float*)d_in[9];
  const float* Wo = (const float*)d_in[10];
  const float* bo = (const float*)d_in[11];
  float* outp = (float*)d_out;

  // workspace carve (~48.1 MB)
  short* qb  = (short*)d_ws;                    // [T][16][128] bf16
  short* kvb = qb + (size_t)4194304;            // [T][2048] bf16 (k|v)
  short* vtb = kvb + (size_t)4194304;           // [8][128][T] bf16 (V^T)
  float* gT  = (float*)(vtb + (size_t)4194304); // [8][T] f32 (logsigmoid)
  float* Gct = gT + 16384;                      // [8][T] f32 (cumsum)
  short* S1  = (short*)(Gct + 16384);           // hsb -> WoT
  short* S2  = S1 + (size_t)4194304;            // WqT -> attn-out
  short* S3  = S2 + (size_t)4194304;            // WkT|WvT

  cvt_bf16<<<4096, 256, 0, stream>>>(hs, S1, 1048576);
  transpose_to_bf16<<<dim3(64, 64), 256, 0, stream>>>(Wq, S2, 2048, 2048);
  transpose_to_bf16<<<dim3(32, 64), 256, 0, stream>>>(Wk, S3, 1024, 2048);
  transpose_to_bf16<<<dim3(32, 64), 256, 0, stream>>>(Wv, S3 + (size_t)1024 * 2048, 1024, 2048);

  gemm_bf16<true><<<dim3(16, 16), 256, 0, stream>>>(S1, S2, bq, bq, 2048, qb, 2048, 2048, 2048);
  gemm_bf16<true><<<dim3(16, 16), 256, 0, stream>>>(S1, S3, bk, bv, 1024, kvb, 2048, 2048, 2048);

  transpose_to_bf16<<<dim3(64, 64), 256, 0, stream>>>(Wo, S1, 2048, 2048);  // hsb dead

  gproj_kernel<<<2048, 256, 0, stream>>>(hs, Wg, bg, gT);
  gscan_kernel<<<8, 512, 0, stream>>>(gT, Gct);

  rope_kernel<<<2048, 192, 0, stream>>>(qb, kvb);
  vtrans_kernel<<<dim3(64, 4, 8), 256, 0, stream>>>((const unsigned short*)kvb,
                                                    (unsigned short*)vtb);

  attn_mfma<<<dim3(8, 32), 256, 0, stream>>>(qb, kvb, vtb, Gct, S2);

  gemm_bf16<false><<<dim3(16, 16), 256, 0, stream>>>(S2, S1, bo, bo, 2048, outp, 2048, 2048, 2048);
}

// Round 6
// 149.571 us; speedup vs baseline: 51.7940x; 1.2530x over previous
//
#include <hip/hip_runtime.h>
#include <hip/hip_bf16.h>
#include <math.h>

#define T_SEQ 2048
#define HID 2048
#define HQ 16
#define HKV 8
#define D_HEAD 128
#define HALF 64
#define SCALE_F 0.08838834764831845f
#define PROJW 4096   // proj row width: q(2048) | k(1024) | v(1024)

typedef __attribute__((ext_vector_type(8))) short bf16x8;
typedef __attribute__((ext_vector_type(4))) float f32x4;

static __device__ __forceinline__ short f2bf(float x) {
  unsigned u = __builtin_bit_cast(unsigned, x);
  unsigned r = (u + 0x7FFF + ((u >> 16) & 1)) >> 16;   // RNE
  return (short)r;
}
static __device__ __forceinline__ float bf2f(unsigned short u) {
  unsigned v = ((unsigned)u) << 16;
  return __builtin_bit_cast(float, v);
}

#define GLDS(gsrc, ldst) \
  __builtin_amdgcn_global_load_lds((const __attribute__((address_space(1))) void*)(gsrc), \
                                   (__attribute__((address_space(3))) void*)(ldst), 16, 0, 0)

// ---------------- elementwise fp32 -> bf16 ----------------
__global__ __launch_bounds__(256)
void cvt_bf16(const float* __restrict__ in, short* __restrict__ out, int n4)
{
  int i = blockIdx.x * blockDim.x + threadIdx.x;
  if (i >= n4) return;
  float4 v = reinterpret_cast<const float4*>(in)[i];
  short4 o;
  o.x = f2bf(v.x); o.y = f2bf(v.y); o.z = f2bf(v.z); o.w = f2bf(v.w);
  reinterpret_cast<short4*>(out)[i] = o;
}

// ------------- transpose fp32 [K][N] -> bf16 [N][out_ld] -------------
__global__ __launch_bounds__(256)
void transpose_to_bf16(const float* __restrict__ in, short* __restrict__ out,
                       int N, int out_ld)
{
  __shared__ float tile[32][33];
  const int k0 = blockIdx.y * 32, n0 = blockIdx.x * 32;
  const int r = threadIdx.x >> 5, c = threadIdx.x & 31;
  #pragma unroll
  for (int i = 0; i < 4; ++i)
    tile[r + i * 8][c] = in[(size_t)(k0 + r + i * 8) * N + n0 + c];
  __syncthreads();
  #pragma unroll
  for (int i = 0; i < 4; ++i)
    out[(size_t)(n0 + r + i * 8) * out_ld + k0 + c] = f2bf(tile[c][r + i * 8]);
}

// ------------- pack concatenated bias [bq|bk|bv] -> bcat[4096] -------------
__global__ __launch_bounds__(256)
void pack_bias(const float* __restrict__ bq, const float* __restrict__ bk,
               const float* __restrict__ bv, float* __restrict__ bcat)
{
  const int i = blockIdx.x * 256 + threadIdx.x;
  bcat[i] = (i < 2048) ? bq[i] : ((i < 3072) ? bk[i - 2048] : bv[i - 3072]);
}

// ---------------- fp32 add: out += part ----------------
__global__ __launch_bounds__(256)
void add_f32(float* __restrict__ out, const float* __restrict__ part, int n4)
{
  int i = blockIdx.x * blockDim.x + threadIdx.x;
  if (i >= n4) return;
  float4 a = reinterpret_cast<float4*>(out)[i];
  const float4 b = reinterpret_cast<const float4*>(part)[i];
  a.x += b.x; a.y += b.y; a.z += b.z; a.w += b.w;
  reinterpret_cast<float4*>(out)[i] = a;
}

// ---------------- bf16 MFMA GEMM (m97 structure, split-K via blockIdx.z) ----------------
// C = A[M][Kst](bf16) @ BT[N][Kst](bf16)^T over K slice [z*klen, (z+1)*klen)
// z==0 -> Cout0 (+bias), z>0 -> Cout1 (no bias). Cout fp32 or bf16.
template <bool OBF>
__global__ __launch_bounds__(256)
void gemm_bf16(const short* __restrict__ A, const short* __restrict__ BT,
               const float* __restrict__ bias, void* __restrict__ Cout0,
               void* __restrict__ Cout1, int N, int Kst, int klen)
{
  __shared__ short As[2][128 * 32];
  __shared__ short Bs[2][128 * 32];
  const int tid = threadIdx.x;
  const int wave = tid >> 6, lane = tid & 63;
  const int bm0 = blockIdx.y * 128, bn0 = blockIdx.x * 128;
  const int z = blockIdx.z;
  const int koff = z * klen;
  const int wm = (wave >> 1) * 64, wn = (wave & 1) * 64;

  const int srow = wave * 32 + (lane >> 2);
  const int scol = (lane & 3) * 8;
  const short* Abase = A + (size_t)(bm0 + srow) * Kst + koff + scol;
  const short* Bbase = BT + (size_t)(bn0 + srow) * Kst + koff + scol;

  f32x4 acc[4][4] = {};

  const int nk = klen >> 5;
#define STAGE(buf, k0)                                                        \
  do {                                                                        \
    GLDS(Abase + (k0), &As[buf][(wave * 32) * 32]);                           \
    GLDS(Abase + (k0) + (size_t)16 * Kst, &As[buf][(wave * 32 + 16) * 32]);   \
    GLDS(Bbase + (k0), &Bs[buf][(wave * 32) * 32]);                           \
    GLDS(Bbase + (k0) + (size_t)16 * Kst, &Bs[buf][(wave * 32 + 16) * 32]);   \
  } while (0)

  STAGE(0, 0);
  __syncthreads();

  const int kof = (lane >> 4) * 8;
  const int rA = wm + (lane & 15);
  const int rB = wn + (lane & 15);

  for (int t = 0; t < nk; ++t) {
    const int cur = t & 1;
    if (t + 1 < nk) STAGE(cur ^ 1, (t + 1) << 5);
    bf16x8 af[4], bfr[4];
    #pragma unroll
    for (int i = 0; i < 4; ++i) {
      af[i]  = *reinterpret_cast<const bf16x8*>(&As[cur][(rA + i * 16) * 32 + kof]);
      bfr[i] = *reinterpret_cast<const bf16x8*>(&Bs[cur][(rB + i * 16) * 32 + kof]);
    }
    #pragma unroll
    for (int i = 0; i < 4; ++i)
      #pragma unroll
      for (int j = 0; j < 4; ++j)
        acc[i][j] = __builtin_amdgcn_mfma_f32_16x16x32_bf16(af[i], bfr[j], acc[i][j], 0, 0, 0);
    __syncthreads();
  }

  void* Cout = z ? Cout1 : Cout0;
  const int crow = wm + (lane >> 4) * 4;
  const int ccol = wn + (lane & 15);
  #pragma unroll
  for (int j = 0; j < 4; ++j) {
    const int col = bn0 + ccol + j * 16;
    const float b = z ? 0.f : bias[col];
    #pragma unroll
    for (int i = 0; i < 4; ++i)
      #pragma unroll
      for (int r = 0; r < 4; ++r) {
        const int row = bm0 + crow + i * 16 + r;
        const float v = acc[i][j][r] + b;
        if constexpr (OBF)
          ((short*)Cout)[(size_t)row * N + col] = f2bf(v);
        else
          ((float*)Cout)[(size_t)row * N + col] = v;
      }
  }
#undef STAGE
}

// ------------- gate projection + log-sigmoid fused -------------
__global__ __launch_bounds__(256)
void gproj_kernel(const float* __restrict__ hs, const float* __restrict__ Wg,
                  const float* __restrict__ bg, float* __restrict__ gT)
{
  const int t = blockIdx.x, tid = threadIdx.x;
  __shared__ float red[256][9];
  float a[8] = {0.f, 0.f, 0.f, 0.f, 0.f, 0.f, 0.f, 0.f};
  for (int cc = tid; cc < HID; cc += 256) {
    const float hv = hs[(size_t)t * HID + cc];
    const float4 w0 = *reinterpret_cast<const float4*>(Wg + (size_t)cc * 8);
    const float4 w1 = *reinterpret_cast<const float4*>(Wg + (size_t)cc * 8 + 4);
    a[0] = fmaf(hv, w0.x, a[0]); a[1] = fmaf(hv, w0.y, a[1]);
    a[2] = fmaf(hv, w0.z, a[2]); a[3] = fmaf(hv, w0.w, a[3]);
    a[4] = fmaf(hv, w1.x, a[4]); a[5] = fmaf(hv, w1.y, a[5]);
    a[6] = fmaf(hv, w1.z, a[6]); a[7] = fmaf(hv, w1.w, a[7]);
  }
  #pragma unroll
  for (int j = 0; j < 8; ++j) red[tid][j] = a[j];
  __syncthreads();
  for (int s = 128; s >= 1; s >>= 1) {
    if (tid < s) {
      #pragma unroll
      for (int j = 0; j < 8; ++j) red[tid][j] += red[tid + s][j];
    }
    __syncthreads();
  }
  if (tid < 8) {
    const float x = red[0][tid] + bg[tid];
    const float nx = -x;
    const float sp = (nx > 20.f) ? nx : log1pf(expf(nx));
    gT[(size_t)tid * T_SEQ + t] = -sp;      // log_sigmoid(x)
  }
}

// ------- parallel inclusive cumsum over T per head -------
__global__ __launch_bounds__(512)
void gscan_kernel(const float* __restrict__ gT, float* __restrict__ Gct)
{
  const int h = blockIdx.x;
  const int tid = threadIdx.x;
  const int wid = tid >> 6, lane = tid & 63;
  __shared__ float wsum[8];

  const float4 v = reinterpret_cast<const float4*>(gT + (size_t)h * T_SEQ)[tid];
  const float p0 = v.x, p1 = p0 + v.y, p2 = p1 + v.z, p3 = p2 + v.w;

  float sc = p3;
  #pragma unroll
  for (int off = 1; off < 64; off <<= 1) {
    const float o = __shfl_up(sc, off, 64);
    if (lane >= off) sc += o;
  }
  if (lane == 63) wsum[wid] = sc;
  __syncthreads();
  float wof = 0.f;
  #pragma unroll
  for (int w = 0; w < 8; ++w) wof += (w < wid) ? wsum[w] : 0.f;

  const float excl = wof + sc - p3;
  reinterpret_cast<float4*>(Gct + (size_t)h * T_SEQ)[tid] =
      make_float4(excl + p0, excl + p1, excl + p2, excl + p3);
}

// ---------------- RoPE (NeoX) in place on proj (q + k regions) ----------------
__global__ __launch_bounds__(192)
void rope_kernel(short* __restrict__ proj)
{
  const int t = blockIdx.x;
  __shared__ float cs[64], sn[64];
  if (threadIdx.x < 64) {
    const int i = threadIdx.x;
    const float f = (float)t * powf(10000.0f, -(float)i / 64.0f);
    cs[i] = cosf(f); sn[i] = sinf(f);
  }
  __syncthreads();
  const int u = threadIdx.x;          // 24 heads x 8 chunks
  const int hh = u >> 3, ch = u & 7;
  short* base = proj + (size_t)t * PROJW +
                ((hh < HQ) ? hh * D_HEAD : 2048 + (hh - HQ) * D_HEAD);
  bf16x8 x1 = *reinterpret_cast<bf16x8*>(base + ch * 8);
  bf16x8 x2 = *reinterpret_cast<bf16x8*>(base + HALF + ch * 8);
  #pragma unroll
  for (int j = 0; j < 8; ++j) {
    const float a = bf2f((unsigned short)x1[j]);
    const float b = bf2f((unsigned short)x2[j]);
    const float cc = cs[ch * 8 + j], ss = sn[ch * 8 + j];
    x1[j] = f2bf(a * cc - b * ss);
    x2[j] = f2bf(b * cc + a * ss);
  }
  *reinterpret_cast<bf16x8*>(base + ch * 8) = x1;
  *reinterpret_cast<bf16x8*>(base + HALF + ch * 8) = x2;
}

// -------- V transpose: proj[t][3072 + hk*128 + d] -> Vt[hk][d][t] (bf16) --------
__global__ __launch_bounds__(256)
void vtrans_kernel(const unsigned short* __restrict__ proj, unsigned short* __restrict__ vt)
{
  __shared__ unsigned short tile[32][33];
  const int tt = blockIdx.x * 32, dd = blockIdx.y * 32, hk = blockIdx.z;
  const int c = threadIdx.x & 31, r0 = (threadIdx.x >> 5) * 4;
  #pragma unroll
  for (int i = 0; i < 4; ++i)
    tile[r0 + i][c] = proj[(size_t)(tt + r0 + i) * PROJW + 3072 + hk * 128 + dd + c];
  __syncthreads();
  #pragma unroll
  for (int i = 0; i < 4; ++i)
    vt[(size_t)(hk * 128 + dd + r0 + i) * T_SEQ + tt + c] = tile[c][r0 + i];
}

// ---------------- MFMA attention ----------------
// q at proj[t][h*128], k at proj[t][2048 + hk*128]; Vt separate.
__global__ __launch_bounds__(256, 1)
void attn_mfma(const short* __restrict__ proj, const short* __restrict__ vt,
               const float* __restrict__ Gct, short* __restrict__ outb)
{
  __shared__ __align__(16) char smem[86528];
  const int hk = blockIdx.x;
  const int tb = blockIdx.y * 64;
  const int tid = threadIdx.x;
  const int wid = tid >> 6, lane = tid & 63;
  const int c = lane & 15, g = lane >> 4;
  const int h = 2 * hk + (wid >> 1);
  const int tw = tb + (wid & 1) * 32;
  const float* Gh = Gct + (size_t)hk * T_SEQ;

  // decay-window start (G monotone down; beyond -90 exp underflows to 0 exactly)
  const float glim = Gh[tb] + 90.0f;
  int lo = 0, hi = tb;
  while (lo < hi) {
    const int mid = (lo + hi) >> 1;
    if (Gh[mid] > glim) lo = mid + 1; else hi = mid;
  }
  const int sfirst = lo & ~63;
  const int nst = ((tb - sfirst) >> 6) + 1;

  // Q fragments (B-operand)
  bf16x8 qf[2][4];
  #pragma unroll
  for (int tt = 0; tt < 2; ++tt)
    #pragma unroll
    for (int kb = 0; kb < 4; ++kb)
      qf[tt][kb] = *reinterpret_cast<const bf16x8*>(
          proj + (size_t)(tw + 16 * tt + c) * PROJW + h * D_HEAD + kb * 32 + g * 8);
  const float gt0 = Gh[tw + c];
  const float gt1 = Gh[tw + 16 + c];
  const float gtw = Gh[tw];
  const int twmax = tw + 31;

  f32x4 accv[2][8] = {};

#define ASTG(buf, s64)                                                                   \
  do {                                                                                   \
    _Pragma("unroll")                                                                    \
    for (int i2 = 0; i2 < 4; ++i2) {                                                     \
      const int cid = tid + 256 * i2;                                                    \
      const int kr = cid >> 4, kc = cid & 15;                                            \
      GLDS(proj + (size_t)((s64) + kr) * PROJW + 2048 + hk * 128 + ((kc ^ (kr & 7)) * 8),\
           smem + (buf) * 16384 + cid * 16);                                             \
      const int vr = cid >> 3, vc = cid & 7;                                             \
      GLDS(vt + (size_t)(hk * 128 + vr) * T_SEQ + (s64) + ((vc ^ (vr & 7)) * 8),         \
           smem + 32768 + (buf) * 16384 + cid * 16);                                     \
    }                                                                                    \
    if (tid < 64) ((float*)(smem + 86016))[(buf) * 64 + tid] = Gh[(s64) + tid];          \
  } while (0)

  ASTG(0, sfirst);
  __syncthreads();

  for (int i = 0; i < nst; ++i) {
    const int cur = i & 1;
    if (i + 1 < nst) ASTG(cur ^ 1, sfirst + (i + 1) * 64);
    const int sbase64 = sfirst + i * 64;
    const float* Gss = (const float*)(smem + 86016) + cur * 64;
    char* Pmy = smem + 65536 + wid * 5120;

    #pragma unroll
    for (int st = 0; st < 2; ++st) {
      const int s0 = sbase64 + st * 32;
      if (s0 > twmax) continue;
      if (gtw - Gss[st * 32 + 31] < -90.0f) continue;

      bf16x8 kf[2][4];
      #pragma unroll
      for (int sg = 0; sg < 2; ++sg)
        #pragma unroll
        for (int kb = 0; kb < 4; ++kb) {
          const int row = st * 32 + 16 * sg + c;
          const int byt = (row * 256 + kb * 64 + g * 16) ^ ((c & 7) << 4);
          kf[sg][kb] = *reinterpret_cast<const bf16x8*>(smem + cur * 16384 + byt);
        }
      f32x4 sa[2][2] = {};
      #pragma unroll
      for (int kb = 0; kb < 4; ++kb)
        #pragma unroll
        for (int sg = 0; sg < 2; ++sg)
          #pragma unroll
          for (int tt = 0; tt < 2; ++tt)
            sa[sg][tt] = __builtin_amdgcn_mfma_f32_16x16x32_bf16(
                kf[sg][kb], qf[tt][kb], sa[sg][tt], 0, 0, 0);

      #pragma unroll
      for (int sg = 0; sg < 2; ++sg) {
        const float4 gs = *reinterpret_cast<const float4*>(&Gss[st * 32 + sg * 16 + g * 4]);
        const float gsv[4] = {gs.x, gs.y, gs.z, gs.w};
        #pragma unroll
        for (int tt = 0; tt < 2; ++tt) {
          const int tg = tw + 16 * tt + c;
          const float gt = tt ? gt1 : gt0;
          const int sg0 = s0 + sg * 16 + g * 4;
          float w[4];
          #pragma unroll
          for (int r = 0; r < 4; ++r) {
            const float dv = sa[sg][tt][r] * SCALE_F;
            const float ww = dv * dv * __expf(gt - gsv[r]);
            w[r] = (sg0 + r <= tg) ? ww : 0.0f;
          }
          uint2 pv;
          pv.x = ((unsigned)(unsigned short)f2bf(w[1]) << 16) | (unsigned short)f2bf(w[0]);
          pv.y = ((unsigned)(unsigned short)f2bf(w[3]) << 16) | (unsigned short)f2bf(w[2]);
          *reinterpret_cast<uint2*>(Pmy + st * 2560 + (c + 16 * tt) * 80 + 8 * g + 32 * sg) = pv;
        }
      }
      asm volatile("s_waitcnt lgkmcnt(0)" ::: "memory");
      __builtin_amdgcn_sched_barrier(0);

      bf16x8 pf[2];
      #pragma unroll
      for (int tt = 0; tt < 2; ++tt)
        pf[tt] = *reinterpret_cast<const bf16x8*>(Pmy + st * 2560 + (c + 16 * tt) * 80 + g * 16);

      #pragma unroll
      for (int db = 0; db < 8; ++db) {
        const int row = 16 * db + c;
        const int byt = (row * 128 + st * 64 + g * 16) ^ ((c & 7) << 4);
        const bf16x8 vf = *reinterpret_cast<const bf16x8*>(smem + 32768 + cur * 16384 + byt);
        #pragma unroll
        for (int tt = 0; tt < 2; ++tt)
          accv[tt][db] = __builtin_amdgcn_mfma_f32_16x16x32_bf16(pf[tt], vf, accv[tt][db], 0, 0, 0);
      }
    }
    __syncthreads();
  }

  char* Wme = smem + wid * 8704;
  #pragma unroll
  for (int tt = 0; tt < 2; ++tt)
    #pragma unroll
    for (int db = 0; db < 8; ++db)
      #pragma unroll
      for (int r = 0; r < 4; ++r)
        *reinterpret_cast<short*>(Wme + (16 * tt + 4 * g + r) * 272 + (16 * db + c) * 2)
            = f2bf(accv[tt][db][r]);
  asm volatile("s_waitcnt lgkmcnt(0)" ::: "memory");
  __builtin_amdgcn_sched_barrier(0);
  #pragma unroll
  for (int e = 0; e < 8; ++e) {
    const int idx = e * 64 + lane;
    const int tr = idx >> 4, d0 = (idx & 15) * 8;
    const bf16x8 vv = *reinterpret_cast<const bf16x8*>(Wme + tr * 272 + d0 * 2);
    *reinterpret_cast<bf16x8*>(outb + ((size_t)(tw + tr) * HQ + h) * D_HEAD + d0) = vv;
  }
#undef ASTG
}

extern "C" void kernel_launch(void* const* d_in, const int* in_sizes, int n_in,
                              void* d_out, int out_size, void* d_ws, size_t ws_size,
                              hipStream_t stream)
{
  const float* hs = (const float*)d_in[1];
  const float* Wq = (const float*)d_in[2];
  const float* bq = (const float*)d_in[3];
  const float* Wk = (const float*)d_in[4];
  const float* bk = (const float*)d_in[5];
  const float* Wv = (const float*)d_in[6];
  const float* bv = (const float*)d_in[7];
  const float* Wg = (const float*)d_in[8];
  const float* bg = (const float*)d_in[9];
  const float* Wo = (const float*)d_in[10];
  const float* bo = (const float*)d_in[11];
  float* outp = (float*)d_out;

  // workspace carve (~44.2 MB, with aliasing)
  short* proj  = (short*)d_ws;                    // [T][4096] bf16 (q|k|v)   16 MB
  short* vtb   = proj + (size_t)T_SEQ * PROJW;    // [8][128][T] bf16          4 MB
  float* gT    = (float*)(vtb + (size_t)HKV * D_HEAD * T_SEQ);
  float* Gct   = gT + 16384;
  float* bcat  = Gct + 16384;                     // [4096] f32
  short* hsb   = (short*)(bcat + 4096);           // [T][2048] bf16            8 MB
  short* BTall = hsb + (size_t)2048 * 2048;       // [4096][2048] bf16        16 MB
  short* WoT     = BTall;            // alias: after QKV GEMM, BTall rows 0..2047
  short* attnout = hsb;              // alias: after QKV GEMM, hsb dead
  float* partial = (float*)proj;     // alias: after attn, proj dead

  // 1) prep
  cvt_bf16<<<4096, 256, 0, stream>>>(hs, hsb, 1048576);
  transpose_to_bf16<<<dim3(64, 64), 256, 0, stream>>>(Wq, BTall, 2048, 2048);
  transpose_to_bf16<<<dim3(32, 64), 256, 0, stream>>>(Wk, BTall + (size_t)2048 * 2048, 1024, 2048);
  transpose_to_bf16<<<dim3(32, 64), 256, 0, stream>>>(Wv, BTall + (size_t)3072 * 2048, 1024, 2048);
  pack_bias<<<16, 256, 0, stream>>>(bq, bk, bv, bcat);

  // 2) fused QKV projection: proj = hsb @ [Wq|Wk|Wv]^T + bcat  (512 blocks)
  gemm_bf16<true><<<dim3(32, 16, 1), 256, 0, stream>>>(
      hsb, BTall, bcat, proj, proj, PROJW, 2048, 2048);

  // 3) Wo transpose into (now-dead) BTall region
  transpose_to_bf16<<<dim3(64, 64), 256, 0, stream>>>(Wo, WoT, 2048, 2048);

  // 4) gate + scan
  gproj_kernel<<<2048, 256, 0, stream>>>(hs, Wg, bg, gT);
  gscan_kernel<<<8, 512, 0, stream>>>(gT, Gct);

  // 5) RoPE + V transpose
  rope_kernel<<<2048, 192, 0, stream>>>(proj);
  vtrans_kernel<<<dim3(64, 4, 8), 256, 0, stream>>>((const unsigned short*)proj,
                                                    (unsigned short*)vtb);

  // 6) attention -> bf16 into hsb region
  attn_mfma<<<dim3(8, 32), 256, 0, stream>>>(proj, vtb, Gct, attnout);

  // 7) output projection, split-K=2 (512 blocks): z=0 -> d_out(+bias), z=1 -> partial
  gemm_bf16<false><<<dim3(16, 16, 2), 256, 0, stream>>>(
      attnout, WoT, bo, outp, partial, 2048, 2048, 1024);
  add_f32<<<4096, 256, 0, stream>>>(outp, partial, 1048576);
}